// Round 1
// baseline (8227.309 us; speedup 1.0000x reference)
//
#include <hip/hip_runtime.h>
#include <math.h>

// Problem constants (match reference setup_inputs)
#define NN 100000
#define EE 3200000
// H = 256, F_IN = 128, G = 64

// ---------------------------------------------------------------------------
// CSR build: in-degree histogram -> exclusive scan -> fill {src, dinv[src]}
// ---------------------------------------------------------------------------
__global__ void zero_int(int* __restrict__ p, int n) {
  int i = blockIdx.x * 256 + threadIdx.x;
  if (i < n) p[i] = 0;
}

__global__ void hist_deg(const int* __restrict__ dst, int* __restrict__ deg, int e) {
  int i = blockIdx.x * 256 + threadIdx.x;
  if (i < e) atomicAdd(&deg[dst[i]], 1);
}

__global__ void calc_dinv(const int* __restrict__ deg, float* __restrict__ dinv, int n) {
  int i = blockIdx.x * 256 + threadIdx.x;
  if (i < n) dinv[i] = 1.0f / sqrtf((float)(deg[i] + 1));
}

// Single-block exclusive scan over N ints (wave shfl scan + cross-wave LDS).
__global__ __launch_bounds__(1024) void scan_excl(const int* __restrict__ deg,
                                                  int* __restrict__ offs, int n) {
  __shared__ int wsum[16];
  __shared__ int s_carry;
  int tid = threadIdx.x;
  int lane = tid & 63, wv = tid >> 6;
  if (tid == 0) s_carry = 0;
  __syncthreads();
  for (int base = 0; base < n; base += 1024) {
    int idx = base + tid;
    int v = (idx < n) ? deg[idx] : 0;
    int x = v;
#pragma unroll
    for (int o = 1; o < 64; o <<= 1) {
      int t = __shfl_up(x, o, 64);
      if (lane >= o) x += t;
    }
    if (lane == 63) wsum[wv] = x;
    __syncthreads();
    int carry = s_carry;
    int woff = 0;
    for (int j = 0; j < wv; ++j) woff += wsum[j];
    if (idx < n) offs[idx] = carry + woff + x - v;
    __syncthreads();
    if (tid == 1023) s_carry = carry + woff + x;  // carry + chunk total
    __syncthreads();
  }
  if (threadIdx.x == 0) offs[n] = s_carry;
}

__global__ void fill_csr(const int* __restrict__ src, const int* __restrict__ dst,
                         const float* __restrict__ dinv, const int* __restrict__ offs,
                         int* __restrict__ fillc, unsigned long long* __restrict__ ent,
                         int e) {
  int i = blockIdx.x * 256 + threadIdx.x;
  if (i >= e) return;
  int d = dst[i], s = src[i];
  int pos = offs[d] + atomicAdd(&fillc[d], 1);
  unsigned long long w = (unsigned long long)(unsigned)__float_as_int(dinv[s]);
  ent[pos] = (w << 32) | (unsigned)s;
}

// ---------------------------------------------------------------------------
// Aggregation: y[v] = dinv[v] * ( sum_e dinv[src_e]*x[src_e] + dinv[v]*x[v] )
// Wave-per-node, lanes span features. F=256: float4/lane. F=128: float2/lane.
// ---------------------------------------------------------------------------
__global__ __launch_bounds__(256) void agg256(const float* __restrict__ x,
    const unsigned long long* __restrict__ ent, const int* __restrict__ offs,
    const float* __restrict__ dinv, float* __restrict__ y, int n) {
  int v = (blockIdx.x * 256 + threadIdx.x) >> 6;
  int lane = threadIdx.x & 63;
  if (v >= n) return;
  float dv = dinv[v];
  const float4* xv = (const float4*)x;
  float4 acc = xv[(size_t)v * 64 + lane];
  acc.x *= dv; acc.y *= dv; acc.z *= dv; acc.w *= dv;
  int s = offs[v], e = offs[v + 1];
  int i = s;
  // 2-edge unroll for memory-level parallelism (independent row loads)
  for (; i + 1 < e; i += 2) {
    unsigned long long p0 = ent[i], p1 = ent[i + 1];
    int s0 = (int)(p0 & 0xffffffffu), s1 = (int)(p1 & 0xffffffffu);
    float w0 = __int_as_float((int)(p0 >> 32));
    float w1 = __int_as_float((int)(p1 >> 32));
    float4 r0 = xv[(size_t)s0 * 64 + lane];
    float4 r1 = xv[(size_t)s1 * 64 + lane];
    acc.x += w0 * r0.x + w1 * r1.x;
    acc.y += w0 * r0.y + w1 * r1.y;
    acc.z += w0 * r0.z + w1 * r1.z;
    acc.w += w0 * r0.w + w1 * r1.w;
  }
  if (i < e) {
    unsigned long long p0 = ent[i];
    int s0 = (int)(p0 & 0xffffffffu);
    float w0 = __int_as_float((int)(p0 >> 32));
    float4 r0 = xv[(size_t)s0 * 64 + lane];
    acc.x += w0 * r0.x; acc.y += w0 * r0.y; acc.z += w0 * r0.z; acc.w += w0 * r0.w;
  }
  acc.x *= dv; acc.y *= dv; acc.z *= dv; acc.w *= dv;
  ((float4*)y)[(size_t)v * 64 + lane] = acc;
}

__global__ __launch_bounds__(256) void agg128(const float* __restrict__ x,
    const unsigned long long* __restrict__ ent, const int* __restrict__ offs,
    const float* __restrict__ dinv, float* __restrict__ y, int n) {
  int v = (blockIdx.x * 256 + threadIdx.x) >> 6;
  int lane = threadIdx.x & 63;
  if (v >= n) return;
  float dv = dinv[v];
  const float2* xv = (const float2*)x;
  float2 acc = xv[(size_t)v * 64 + lane];
  acc.x *= dv; acc.y *= dv;
  int s = offs[v], e = offs[v + 1];
  int i = s;
  for (; i + 1 < e; i += 2) {
    unsigned long long p0 = ent[i], p1 = ent[i + 1];
    int s0 = (int)(p0 & 0xffffffffu), s1 = (int)(p1 & 0xffffffffu);
    float w0 = __int_as_float((int)(p0 >> 32));
    float w1 = __int_as_float((int)(p1 >> 32));
    float2 r0 = xv[(size_t)s0 * 64 + lane];
    float2 r1 = xv[(size_t)s1 * 64 + lane];
    acc.x += w0 * r0.x + w1 * r1.x;
    acc.y += w0 * r0.y + w1 * r1.y;
  }
  if (i < e) {
    unsigned long long p0 = ent[i];
    int s0 = (int)(p0 & 0xffffffffu);
    float w0 = __int_as_float((int)(p0 >> 32));
    float2 r0 = xv[(size_t)s0 * 64 + lane];
    acc.x += w0 * r0.x; acc.y += w0 * r0.y;
  }
  acc.x *= dv; acc.y *= dv;
  ((float2*)y)[(size_t)v * 64 + lane] = acc;
}

// ---------------------------------------------------------------------------
// fp32 GEMM: C[M,256] = A[M,K] @ W[K,256] + bias, optional ReLU.
// 64x64 tile, BK=32, 256 threads, 4x4 micro-tile per thread.
// ---------------------------------------------------------------------------
#define BM 64
#define BN 64
#define BK 32
__global__ __launch_bounds__(256) void gemm_bias_act(
    const float* __restrict__ A, const float* __restrict__ W,
    const float* __restrict__ bias, float* __restrict__ C,
    int M, int K, int do_relu) {
  __shared__ float As[BK][BM + 4];
  __shared__ float Bs[BK][BN + 4];
  int tid = threadIdx.x;
  int row0 = blockIdx.x * BM;
  int col0 = blockIdx.y * BN;
  int tn = tid & 15, tm = tid >> 4;
  int am = tid >> 3, ak = (tid & 7) * 4;
  int bk = tid >> 4, bn4 = (tid & 15) * 4;
  float acc[4][4] = {};
  for (int k0 = 0; k0 < K; k0 += BK) {
#pragma unroll
    for (int hh = 0; hh < 2; ++hh) {
      int m = am + hh * 32;
      int r = row0 + m; if (r > M - 1) r = M - 1;
      float4 a4 = *(const float4*)(A + (size_t)r * K + k0 + ak);
      As[ak + 0][m] = a4.x; As[ak + 1][m] = a4.y;
      As[ak + 2][m] = a4.z; As[ak + 3][m] = a4.w;
    }
#pragma unroll
    for (int hh = 0; hh < 2; ++hh) {
      int k = bk + hh * 16;
      float4 b4 = *(const float4*)(W + (size_t)(k0 + k) * 256 + col0 + bn4);
      *(float4*)&Bs[k][bn4] = b4;
    }
    __syncthreads();
#pragma unroll
    for (int k = 0; k < BK; ++k) {
      float4 a = *(const float4*)&As[k][tm * 4];
      float4 b = *(const float4*)&Bs[k][tn * 4];
      acc[0][0] += a.x * b.x; acc[0][1] += a.x * b.y; acc[0][2] += a.x * b.z; acc[0][3] += a.x * b.w;
      acc[1][0] += a.y * b.x; acc[1][1] += a.y * b.y; acc[1][2] += a.y * b.z; acc[1][3] += a.y * b.w;
      acc[2][0] += a.z * b.x; acc[2][1] += a.z * b.y; acc[2][2] += a.z * b.z; acc[2][3] += a.z * b.w;
      acc[3][0] += a.w * b.x; acc[3][1] += a.w * b.y; acc[3][2] += a.w * b.z; acc[3][3] += a.w * b.w;
    }
    __syncthreads();
  }
  float4 bb = *(const float4*)(bias + col0 + tn * 4);
#pragma unroll
  for (int i = 0; i < 4; ++i) {
    int r = row0 + tm * 4 + i;
    if (r < M) {
      float4 o;
      o.x = acc[i][0] + bb.x; o.y = acc[i][1] + bb.y;
      o.z = acc[i][2] + bb.z; o.w = acc[i][3] + bb.w;
      if (do_relu) {
        o.x = fmaxf(o.x, 0.f); o.y = fmaxf(o.y, 0.f);
        o.z = fmaxf(o.z, 0.f); o.w = fmaxf(o.w, 0.f);
      }
      *(float4*)(C + (size_t)r * 256 + col0 + tn * 4) = o;
    }
  }
}

// ---------------------------------------------------------------------------
// Pooling: batch is sorted; per-block run-length accumulate then atomicAdd.
// ---------------------------------------------------------------------------
__global__ __launch_bounds__(256) void pool_sum(const float* __restrict__ h,
    const int* __restrict__ batch, float* __restrict__ sums, int n) {
  int f = threadIdx.x;           // 0..255 feature
  int v0 = blockIdx.x * 128;
  if (v0 >= n) return;
  int vend = min(v0 + 128, n);
  int cur = batch[v0];
  float acc = 0.f;
  for (int v = v0; v < vend; ++v) {
    int b = batch[v];
    if (b != cur) { atomicAdd(&sums[cur * 256 + f], acc); acc = 0.f; cur = b; }
    acc += h[(size_t)v * 256 + f];
  }
  atomicAdd(&sums[cur * 256 + f], acc);
}

__global__ void count_batch(const int* __restrict__ batch, float* __restrict__ cnts, int n) {
  int i = blockIdx.x * 256 + threadIdx.x;
  if (i < n) atomicAdd(&cnts[batch[i]], 1.0f);
}

// z[g,f] = (sums[g,:]/max(cnt,1)) @ lin0_W[:,f] + lin0_b[f]   (64 blocks x 128 thr)
__global__ __launch_bounds__(128) void pool_lin(const float* __restrict__ sums,
    const float* __restrict__ cnts, const float* __restrict__ W128,
    const float* __restrict__ b128, float* __restrict__ z) {
  int g = blockIdx.x, f = threadIdx.x;
  float inv = 1.0f / fmaxf(cnts[g], 1.0f);
  float acc = 0.f;
  for (int k = 0; k < 256; ++k)
    acc += (sums[g * 256 + k] * inv) * W128[k * 128 + f];
  z[g * 128 + f] = acc + b128[f];
}

// ---------------------------------------------------------------------------
// Final triplet outputs. out layout: z0[8192] z1[8192] z2[8192] correct[1]
// score_p[64] score_n[64] correct_score[1]
// ---------------------------------------------------------------------------
__global__ __launch_bounds__(64) void final_triplet(const float* __restrict__ z,
    const float* __restrict__ lin_W, const float* __restrict__ lin_b,
    float* __restrict__ out) {
  int g = threadIdx.x;  // 0..63, one wave
  const float* z0 = z;
  const float* z1 = z + 8192;
  const float* z2 = z + 16384;
  float dp = 0.f, dn = 0.f;
  float y1 = lin_b[0], y2 = lin_b[0];
  for (int f = 0; f < 128; ++f) {
    float a = z0[g * 128 + f], b = z1[g * 128 + f], c = z2[g * 128 + f];
    float d1 = a - b + 1e-6f, d2 = a - c + 1e-6f;
    dp += d1 * d1; dn += d2 * d2;
    float w0 = lin_W[f], w1 = lin_W[128 + f];
    y1 += a * w0 + b * w1;
    y2 += a * w0 + c * w1;
  }
  dp = sqrtf(dp); dn = sqrtf(dn);
  float sp = 1.f / (1.f + expf(-y1));
  float sn = 1.f / (1.f + expf(-y2));
  out[24577 + g] = sp;
  out[24641 + g] = sn;
  unsigned long long m1 = __ballot(dn - dp > 0.f);
  unsigned long long m2 = __ballot(sp - sn > 0.f);
  if (g == 0) {
    out[24576] = (float)__popcll(m1);
    out[24705] = (float)__popcll(m2);
  }
}

// ---------------------------------------------------------------------------
extern "C" void kernel_launch(void* const* d_in, const int* in_sizes, int n_in,
                              void* d_out, int out_size, void* d_ws, size_t ws_size,
                              hipStream_t stream) {
  const float* xin[3]  = {(const float*)d_in[0], (const float*)d_in[1], (const float*)d_in[2]};
  const int* ei[3]     = {(const int*)d_in[3], (const int*)d_in[4], (const int*)d_in[5]};
  const int* batch[3]  = {(const int*)d_in[6], (const int*)d_in[7], (const int*)d_in[8]};
  const float* W0 = (const float*)d_in[9],  *b0 = (const float*)d_in[10];
  const float* W1 = (const float*)d_in[11], *b1 = (const float*)d_in[12];
  const float* W2 = (const float*)d_in[13], *b2 = (const float*)d_in[14];
  const float* lin0W = (const float*)d_in[15], *lin0b = (const float*)d_in[16];
  const float* linW  = (const float*)d_in[17], *linb  = (const float*)d_in[18];
  float* out = (float*)d_out;

  // workspace carve (all 16B-aligned by construction)
  float* y = (float*)d_ws;                         // N*256 fp32   = 102.4 MB
  float* h = y + (size_t)NN * 256;                 // N*256 fp32   = 102.4 MB
  unsigned long long* ent = (unsigned long long*)(h + (size_t)NN * 256);  // E*8B = 25.6 MB
  int* deg   = (int*)(ent + EE);                   // N ints  -- zeroed region start
  int* fillc = deg + NN;                           // N ints
  float* sums = (float*)(fillc + NN);              // 64*256 floats
  float* cnts = sums + 64 * 256;                   // 64 floats
  int zero_elems = NN + NN + 64 * 256 + 64;        // deg..cnts contiguous
  float* dinv = cnts + 64;                         // N floats
  int* offs = (int*)(dinv + NN);                   // N+1 ints

  const int EB = (EE + 255) / 256;
  const int NB = (NN + 255) / 256;
  dim3 ggrid((NN + BM - 1) / BM, 256 / BN);

  for (int g = 0; g < 3; ++g) {
    const int* src = ei[g];
    const int* dst = ei[g] + EE;
    zero_int<<<(zero_elems + 255) / 256, 256, 0, stream>>>(deg, zero_elems);
    hist_deg<<<EB, 256, 0, stream>>>(dst, deg, EE);
    calc_dinv<<<NB, 256, 0, stream>>>(deg, dinv, NN);
    scan_excl<<<1, 1024, 0, stream>>>(deg, offs, NN);
    fill_csr<<<EB, 256, 0, stream>>>(src, dst, dinv, offs, fillc, ent, EE);

    // layer 0: aggregate input (F=128), then GEMM K=128 -> h, ReLU
    agg128<<<(NN + 3) / 4, 256, 0, stream>>>(xin[g], ent, offs, dinv, y, NN);
    gemm_bias_act<<<ggrid, 256, 0, stream>>>(y, W0, b0, h, NN, 128, 1);
    // layer 1
    agg256<<<(NN + 3) / 4, 256, 0, stream>>>(h, ent, offs, dinv, y, NN);
    gemm_bias_act<<<ggrid, 256, 0, stream>>>(y, W1, b1, h, NN, 256, 1);
    // layer 2 (no relu)
    agg256<<<(NN + 3) / 4, 256, 0, stream>>>(h, ent, offs, dinv, y, NN);
    gemm_bias_act<<<ggrid, 256, 0, stream>>>(y, W2, b2, h, NN, 256, 0);

    // pool + lin0 -> z_g written directly into d_out
    pool_sum<<<(NN + 127) / 128, 256, 0, stream>>>(h, batch[g], sums, NN);
    count_batch<<<NB, 256, 0, stream>>>(batch[g], cnts, NN);
    pool_lin<<<64, 128, 0, stream>>>(sums, cnts, lin0W, lin0b, out + g * 8192);
  }

  final_triplet<<<1, 64, 0, stream>>>(out, linW, linb, out);
}

// Round 2
// 6294.656 us; speedup vs baseline: 1.3070x; 1.3070x over previous
//
#include <hip/hip_runtime.h>
#include <math.h>

// Problem constants (match reference setup_inputs)
#define NN 100000
#define EE 3200000
// H = 256, F_IN = 128, G = 64

// ---------------------------------------------------------------------------
// CSR build: in-degree histogram -> exclusive scan -> fill {src, dinv[src]}
// ---------------------------------------------------------------------------
__global__ void zero_int(int* __restrict__ p, int n) {
  int i = blockIdx.x * 256 + threadIdx.x;
  if (i < n) p[i] = 0;
}

__global__ void hist_deg(const int* __restrict__ dst, int* __restrict__ deg, int e) {
  int i = blockIdx.x * 256 + threadIdx.x;
  if (i < e) atomicAdd(&deg[dst[i]], 1);
}

__global__ void calc_dinv(const int* __restrict__ deg, float* __restrict__ dinv, int n) {
  int i = blockIdx.x * 256 + threadIdx.x;
  if (i < n) dinv[i] = 1.0f / sqrtf((float)(deg[i] + 1));
}

// Single-block exclusive scan over N ints (wave shfl scan + cross-wave LDS).
__global__ __launch_bounds__(1024) void scan_excl(const int* __restrict__ deg,
                                                  int* __restrict__ offs, int n) {
  __shared__ int wsum[16];
  __shared__ int s_carry;
  int tid = threadIdx.x;
  int lane = tid & 63, wv = tid >> 6;
  if (tid == 0) s_carry = 0;
  __syncthreads();
  for (int base = 0; base < n; base += 1024) {
    int idx = base + tid;
    int v = (idx < n) ? deg[idx] : 0;
    int x = v;
#pragma unroll
    for (int o = 1; o < 64; o <<= 1) {
      int t = __shfl_up(x, o, 64);
      if (lane >= o) x += t;
    }
    if (lane == 63) wsum[wv] = x;
    __syncthreads();
    int carry = s_carry;
    int woff = 0;
    for (int j = 0; j < wv; ++j) woff += wsum[j];
    if (idx < n) offs[idx] = carry + woff + x - v;
    __syncthreads();
    if (tid == 1023) s_carry = carry + woff + x;  // carry + chunk total
    __syncthreads();
  }
  if (threadIdx.x == 0) offs[n] = s_carry;
}

__global__ void fill_csr(const int* __restrict__ src, const int* __restrict__ dst,
                         const float* __restrict__ dinv, const int* __restrict__ offs,
                         int* __restrict__ fillc, unsigned long long* __restrict__ ent,
                         int e) {
  int i = blockIdx.x * 256 + threadIdx.x;
  if (i >= e) return;
  int d = dst[i], s = src[i];
  int pos = offs[d] + atomicAdd(&fillc[d], 1);
  unsigned long long w = (unsigned long long)(unsigned)__float_as_int(dinv[s]);
  ent[pos] = (w << 32) | (unsigned)s;
}

// ---------------------------------------------------------------------------
// Aggregation: y[v] = dinv[v] * ( sum_e dinv[src_e]*x[src_e] + dinv[v]*x[v] )
// Wave-per-node, lanes span features. F=256: float4/lane. F=128: float2/lane.
// ---------------------------------------------------------------------------
__global__ __launch_bounds__(256) void agg256(const float* __restrict__ x,
    const unsigned long long* __restrict__ ent, const int* __restrict__ offs,
    const float* __restrict__ dinv, float* __restrict__ y, int n) {
  int v = (blockIdx.x * 256 + threadIdx.x) >> 6;
  int lane = threadIdx.x & 63;
  if (v >= n) return;
  float dv = dinv[v];
  const float4* xv = (const float4*)x;
  float4 acc = xv[(size_t)v * 64 + lane];
  acc.x *= dv; acc.y *= dv; acc.z *= dv; acc.w *= dv;
  int s = offs[v], e = offs[v + 1];
  int i = s;
  // 2-edge unroll for memory-level parallelism (independent row loads)
  for (; i + 1 < e; i += 2) {
    unsigned long long p0 = ent[i], p1 = ent[i + 1];
    int s0 = (int)(p0 & 0xffffffffu), s1 = (int)(p1 & 0xffffffffu);
    float w0 = __int_as_float((int)(p0 >> 32));
    float w1 = __int_as_float((int)(p1 >> 32));
    float4 r0 = xv[(size_t)s0 * 64 + lane];
    float4 r1 = xv[(size_t)s1 * 64 + lane];
    acc.x += w0 * r0.x + w1 * r1.x;
    acc.y += w0 * r0.y + w1 * r1.y;
    acc.z += w0 * r0.z + w1 * r1.z;
    acc.w += w0 * r0.w + w1 * r1.w;
  }
  if (i < e) {
    unsigned long long p0 = ent[i];
    int s0 = (int)(p0 & 0xffffffffu);
    float w0 = __int_as_float((int)(p0 >> 32));
    float4 r0 = xv[(size_t)s0 * 64 + lane];
    acc.x += w0 * r0.x; acc.y += w0 * r0.y; acc.z += w0 * r0.z; acc.w += w0 * r0.w;
  }
  acc.x *= dv; acc.y *= dv; acc.z *= dv; acc.w *= dv;
  ((float4*)y)[(size_t)v * 64 + lane] = acc;
}

__global__ __launch_bounds__(256) void agg128(const float* __restrict__ x,
    const unsigned long long* __restrict__ ent, const int* __restrict__ offs,
    const float* __restrict__ dinv, float* __restrict__ y, int n) {
  int v = (blockIdx.x * 256 + threadIdx.x) >> 6;
  int lane = threadIdx.x & 63;
  if (v >= n) return;
  float dv = dinv[v];
  const float2* xv = (const float2*)x;
  float2 acc = xv[(size_t)v * 64 + lane];
  acc.x *= dv; acc.y *= dv;
  int s = offs[v], e = offs[v + 1];
  int i = s;
  for (; i + 1 < e; i += 2) {
    unsigned long long p0 = ent[i], p1 = ent[i + 1];
    int s0 = (int)(p0 & 0xffffffffu), s1 = (int)(p1 & 0xffffffffu);
    float w0 = __int_as_float((int)(p0 >> 32));
    float w1 = __int_as_float((int)(p1 >> 32));
    float2 r0 = xv[(size_t)s0 * 64 + lane];
    float2 r1 = xv[(size_t)s1 * 64 + lane];
    acc.x += w0 * r0.x + w1 * r1.x;
    acc.y += w0 * r0.y + w1 * r1.y;
  }
  if (i < e) {
    unsigned long long p0 = ent[i];
    int s0 = (int)(p0 & 0xffffffffu);
    float w0 = __int_as_float((int)(p0 >> 32));
    float2 r0 = xv[(size_t)s0 * 64 + lane];
    acc.x += w0 * r0.x; acc.y += w0 * r0.y;
  }
  acc.x *= dv; acc.y *= dv;
  ((float2*)y)[(size_t)v * 64 + lane] = acc;
}

// ---------------------------------------------------------------------------
// fp32 GEMM: C[M,256] = A[M,K] @ W[K,256] + bias, optional ReLU.
// 64x64 tile, BK=32, 256 threads, 4x4 micro-tile per thread.
// ---------------------------------------------------------------------------
#define BM 64
#define BN 64
#define BK 32
__global__ __launch_bounds__(256) void gemm_bias_act(
    const float* __restrict__ A, const float* __restrict__ W,
    const float* __restrict__ bias, float* __restrict__ C,
    int M, int K, int do_relu) {
  __shared__ float As[BK][BM + 4];
  __shared__ float Bs[BK][BN + 4];
  int tid = threadIdx.x;
  int row0 = blockIdx.x * BM;
  int col0 = blockIdx.y * BN;
  int tn = tid & 15, tm = tid >> 4;
  int am = tid >> 3, ak = (tid & 7) * 4;
  int bk = tid >> 4, bn4 = (tid & 15) * 4;
  float acc[4][4] = {};
  for (int k0 = 0; k0 < K; k0 += BK) {
#pragma unroll
    for (int hh = 0; hh < 2; ++hh) {
      int m = am + hh * 32;
      int r = row0 + m; if (r > M - 1) r = M - 1;
      float4 a4 = *(const float4*)(A + (size_t)r * K + k0 + ak);
      As[ak + 0][m] = a4.x; As[ak + 1][m] = a4.y;
      As[ak + 2][m] = a4.z; As[ak + 3][m] = a4.w;
    }
#pragma unroll
    for (int hh = 0; hh < 2; ++hh) {
      int k = bk + hh * 16;
      float4 b4 = *(const float4*)(W + (size_t)(k0 + k) * 256 + col0 + bn4);
      *(float4*)&Bs[k][bn4] = b4;
    }
    __syncthreads();
#pragma unroll
    for (int k = 0; k < BK; ++k) {
      float4 a = *(const float4*)&As[k][tm * 4];
      float4 b = *(const float4*)&Bs[k][tn * 4];
      acc[0][0] += a.x * b.x; acc[0][1] += a.x * b.y; acc[0][2] += a.x * b.z; acc[0][3] += a.x * b.w;
      acc[1][0] += a.y * b.x; acc[1][1] += a.y * b.y; acc[1][2] += a.y * b.z; acc[1][3] += a.y * b.w;
      acc[2][0] += a.z * b.x; acc[2][1] += a.z * b.y; acc[2][2] += a.z * b.z; acc[2][3] += a.z * b.w;
      acc[3][0] += a.w * b.x; acc[3][1] += a.w * b.y; acc[3][2] += a.w * b.z; acc[3][3] += a.w * b.w;
    }
    __syncthreads();
  }
  float4 bb = *(const float4*)(bias + col0 + tn * 4);
#pragma unroll
  for (int i = 0; i < 4; ++i) {
    int r = row0 + tm * 4 + i;
    if (r < M) {
      float4 o;
      o.x = acc[i][0] + bb.x; o.y = acc[i][1] + bb.y;
      o.z = acc[i][2] + bb.z; o.w = acc[i][3] + bb.w;
      if (do_relu) {
        o.x = fmaxf(o.x, 0.f); o.y = fmaxf(o.y, 0.f);
        o.z = fmaxf(o.z, 0.f); o.w = fmaxf(o.w, 0.f);
      }
      *(float4*)(C + (size_t)r * 256 + col0 + tn * 4) = o;
    }
  }
}

// ---------------------------------------------------------------------------
// Pooling: batch is sorted; per-block run-length accumulate then atomicAdd.
// Counting is fused here: thread f==0 adds the run length once per run
// (a few hundred atomics total vs 100K serialized same-address float atomics).
// ---------------------------------------------------------------------------
__global__ __launch_bounds__(256) void pool_sum(const float* __restrict__ h,
    const int* __restrict__ batch, float* __restrict__ sums,
    float* __restrict__ cnts, int n) {
  int f = threadIdx.x;           // 0..255 feature
  int v0 = blockIdx.x * 128;
  if (v0 >= n) return;
  int vend = min(v0 + 128, n);
  int cur = batch[v0];
  float acc = 0.f;
  int cnt = 0;
  for (int v = v0; v < vend; ++v) {
    int b = batch[v];
    if (b != cur) {
      atomicAdd(&sums[cur * 256 + f], acc);
      if (f == 0) atomicAdd(&cnts[cur], (float)cnt);
      acc = 0.f; cnt = 0; cur = b;
    }
    acc += h[(size_t)v * 256 + f];
    cnt++;
  }
  atomicAdd(&sums[cur * 256 + f], acc);
  if (f == 0) atomicAdd(&cnts[cur], (float)cnt);
}

// z[g,f] = (sums[g,:]/max(cnt,1)) @ lin0_W[:,f] + lin0_b[f]   (64 blocks x 128 thr)
__global__ __launch_bounds__(128) void pool_lin(const float* __restrict__ sums,
    const float* __restrict__ cnts, const float* __restrict__ W128,
    const float* __restrict__ b128, float* __restrict__ z) {
  int g = blockIdx.x, f = threadIdx.x;
  float inv = 1.0f / fmaxf(cnts[g], 1.0f);
  float acc = 0.f;
  for (int k = 0; k < 256; ++k)
    acc += (sums[g * 256 + k] * inv) * W128[k * 128 + f];
  z[g * 128 + f] = acc + b128[f];
}

// ---------------------------------------------------------------------------
// Final triplet outputs. out layout: z0[8192] z1[8192] z2[8192] correct[1]
// score_p[64] score_n[64] correct_score[1]
// ---------------------------------------------------------------------------
__global__ __launch_bounds__(64) void final_triplet(const float* __restrict__ z,
    const float* __restrict__ lin_W, const float* __restrict__ lin_b,
    float* __restrict__ out) {
  int g = threadIdx.x;  // 0..63, one wave
  const float* z0 = z;
  const float* z1 = z + 8192;
  const float* z2 = z + 16384;
  float dp = 0.f, dn = 0.f;
  float y1 = lin_b[0], y2 = lin_b[0];
  for (int f = 0; f < 128; ++f) {
    float a = z0[g * 128 + f], b = z1[g * 128 + f], c = z2[g * 128 + f];
    float d1 = a - b + 1e-6f, d2 = a - c + 1e-6f;
    dp += d1 * d1; dn += d2 * d2;
    float w0 = lin_W[f], w1 = lin_W[128 + f];
    y1 += a * w0 + b * w1;
    y2 += a * w0 + c * w1;
  }
  dp = sqrtf(dp); dn = sqrtf(dn);
  float sp = 1.f / (1.f + expf(-y1));
  float sn = 1.f / (1.f + expf(-y2));
  out[24577 + g] = sp;
  out[24641 + g] = sn;
  unsigned long long m1 = __ballot(dn - dp > 0.f);
  unsigned long long m2 = __ballot(sp - sn > 0.f);
  if (g == 0) {
    out[24576] = (float)__popcll(m1);
    out[24705] = (float)__popcll(m2);
  }
}

// ---------------------------------------------------------------------------
extern "C" void kernel_launch(void* const* d_in, const int* in_sizes, int n_in,
                              void* d_out, int out_size, void* d_ws, size_t ws_size,
                              hipStream_t stream) {
  const float* xin[3]  = {(const float*)d_in[0], (const float*)d_in[1], (const float*)d_in[2]};
  const int* ei[3]     = {(const int*)d_in[3], (const int*)d_in[4], (const int*)d_in[5]};
  const int* batch[3]  = {(const int*)d_in[6], (const int*)d_in[7], (const int*)d_in[8]};
  const float* W0 = (const float*)d_in[9],  *b0 = (const float*)d_in[10];
  const float* W1 = (const float*)d_in[11], *b1 = (const float*)d_in[12];
  const float* W2 = (const float*)d_in[13], *b2 = (const float*)d_in[14];
  const float* lin0W = (const float*)d_in[15], *lin0b = (const float*)d_in[16];
  const float* linW  = (const float*)d_in[17], *linb  = (const float*)d_in[18];
  float* out = (float*)d_out;

  // workspace carve (all 16B-aligned by construction)
  float* y = (float*)d_ws;                         // N*256 fp32   = 102.4 MB
  float* h = y + (size_t)NN * 256;                 // N*256 fp32   = 102.4 MB
  unsigned long long* ent = (unsigned long long*)(h + (size_t)NN * 256);  // E*8B = 25.6 MB
  int* deg   = (int*)(ent + EE);                   // N ints  -- zeroed region start
  int* fillc = deg + NN;                           // N ints
  float* sums = (float*)(fillc + NN);              // 64*256 floats
  float* cnts = sums + 64 * 256;                   // 64 floats
  int zero_elems = NN + NN + 64 * 256 + 64;        // deg..cnts contiguous
  float* dinv = cnts + 64;                         // N floats
  int* offs = (int*)(dinv + NN);                   // N+1 ints

  const int EB = (EE + 255) / 256;
  const int NB = (NN + 255) / 256;
  dim3 ggrid((NN + BM - 1) / BM, 256 / BN);

  for (int g = 0; g < 3; ++g) {
    const int* src = ei[g];
    const int* dst = ei[g] + EE;
    zero_int<<<(zero_elems + 255) / 256, 256, 0, stream>>>(deg, zero_elems);
    hist_deg<<<EB, 256, 0, stream>>>(dst, deg, EE);
    calc_dinv<<<NB, 256, 0, stream>>>(deg, dinv, NN);
    scan_excl<<<1, 1024, 0, stream>>>(deg, offs, NN);
    fill_csr<<<EB, 256, 0, stream>>>(src, dst, dinv, offs, fillc, ent, EE);

    // layer 0: aggregate input (F=128), then GEMM K=128 -> h, ReLU
    agg128<<<(NN + 3) / 4, 256, 0, stream>>>(xin[g], ent, offs, dinv, y, NN);
    gemm_bias_act<<<ggrid, 256, 0, stream>>>(y, W0, b0, h, NN, 128, 1);
    // layer 1
    agg256<<<(NN + 3) / 4, 256, 0, stream>>>(h, ent, offs, dinv, y, NN);
    gemm_bias_act<<<ggrid, 256, 0, stream>>>(y, W1, b1, h, NN, 256, 1);
    // layer 2 (no relu)
    agg256<<<(NN + 3) / 4, 256, 0, stream>>>(h, ent, offs, dinv, y, NN);
    gemm_bias_act<<<ggrid, 256, 0, stream>>>(y, W2, b2, h, NN, 256, 0);

    // pool (+fused count) + lin0 -> z_g written directly into d_out
    pool_sum<<<(NN + 127) / 128, 256, 0, stream>>>(h, batch[g], sums, cnts, NN);
    pool_lin<<<64, 128, 0, stream>>>(sums, cnts, lin0W, lin0b, out + g * 8192);
  }

  final_triplet<<<1, 64, 0, stream>>>(out, linW, linb, out);
}

// Round 3
// 3838.714 us; speedup vs baseline: 2.1432x; 1.6398x over previous
//
#include <hip/hip_runtime.h>
#include <math.h>

// Problem constants (match reference setup_inputs)
#define NN 100000
#define EE 3200000
// H = 256, F_IN = 128, G = 64

typedef __attribute__((ext_vector_type(8))) short bf16x8;
typedef __attribute__((ext_vector_type(4))) float f32x4;

// fp32 -> bf16 (round to nearest even), raw ushort
__device__ __forceinline__ unsigned short f2b(float f) {
  unsigned u = __float_as_uint(f);
  u += 0x7fffu + ((u >> 16) & 1u);
  return (unsigned short)(u >> 16);
}
// bf16 (raw ushort) -> fp32
__device__ __forceinline__ float b2f(unsigned short s) {
  return __uint_as_float(((unsigned)s) << 16);
}
__device__ __forceinline__ float blo(unsigned u) { return __uint_as_float(u << 16); }
__device__ __forceinline__ float bhi(unsigned u) { return __uint_as_float(u & 0xffff0000u); }
__device__ __forceinline__ unsigned pack2(float lo, float hi) {
  return ((unsigned)f2b(hi) << 16) | (unsigned)f2b(lo);
}

// ---------------------------------------------------------------------------
// CSR build: in-degree histogram -> exclusive scan -> fill {src, dinv[src]}
// ---------------------------------------------------------------------------
__global__ void zero_int(int* __restrict__ p, int n) {
  int i = blockIdx.x * 256 + threadIdx.x;
  if (i < n) p[i] = 0;
}

__global__ void hist_deg(const int* __restrict__ dst, int* __restrict__ deg, int e) {
  int i = blockIdx.x * 256 + threadIdx.x;
  if (i < e) atomicAdd(&deg[dst[i]], 1);
}

__global__ void calc_dinv(const int* __restrict__ deg, float* __restrict__ dinv, int n) {
  int i = blockIdx.x * 256 + threadIdx.x;
  if (i < n) dinv[i] = 1.0f / sqrtf((float)(deg[i] + 1));
}

// Single-block exclusive scan over N ints (wave shfl scan + cross-wave LDS).
__global__ __launch_bounds__(1024) void scan_excl(const int* __restrict__ deg,
                                                  int* __restrict__ offs, int n) {
  __shared__ int wsum[16];
  __shared__ int s_carry;
  int tid = threadIdx.x;
  int lane = tid & 63, wv = tid >> 6;
  if (tid == 0) s_carry = 0;
  __syncthreads();
  for (int base = 0; base < n; base += 1024) {
    int idx = base + tid;
    int v = (idx < n) ? deg[idx] : 0;
    int x = v;
#pragma unroll
    for (int o = 1; o < 64; o <<= 1) {
      int t = __shfl_up(x, o, 64);
      if (lane >= o) x += t;
    }
    if (lane == 63) wsum[wv] = x;
    __syncthreads();
    int carry = s_carry;
    int woff = 0;
    for (int j = 0; j < wv; ++j) woff += wsum[j];
    if (idx < n) offs[idx] = carry + woff + x - v;
    __syncthreads();
    if (tid == 1023) s_carry = carry + woff + x;  // carry + chunk total
    __syncthreads();
  }
  if (threadIdx.x == 0) offs[n] = s_carry;
}

__global__ void fill_csr(const int* __restrict__ src, const int* __restrict__ dst,
                         const float* __restrict__ dinv, const int* __restrict__ offs,
                         int* __restrict__ fillc, unsigned long long* __restrict__ ent,
                         int e) {
  int i = blockIdx.x * 256 + threadIdx.x;
  if (i >= e) return;
  int d = dst[i], s = src[i];
  int pos = offs[d] + atomicAdd(&fillc[d], 1);
  unsigned long long w = (unsigned long long)(unsigned)__float_as_int(dinv[s]);
  ent[pos] = (w << 32) | (unsigned)s;
}

// ---------------------------------------------------------------------------
// dtype converters
// ---------------------------------------------------------------------------
// fp32 [n] -> bf16 [n]; n % 4 == 0. One thread = 4 elems.
__global__ void conv_bf(const float* __restrict__ in, unsigned* __restrict__ out, int n4) {
  int i = blockIdx.x * 256 + threadIdx.x;
  if (i >= n4) return;
  float4 v = ((const float4*)in)[i];
  ((uint2*)out)[i] = make_uint2(pack2(v.x, v.y), pack2(v.z, v.w));
}

// W[K][256] fp32 -> Wt[256][K] bf16 (transposed for gemm B^T operand)
__global__ void conv_wt(const float* __restrict__ W, unsigned short* __restrict__ Wt, int K) {
  int i = blockIdx.x * 256 + threadIdx.x;
  if (i >= 256 * K) return;
  int nn = i / K, kk = i - nn * K;
  Wt[i] = f2b(W[(size_t)kk * 256 + nn]);
}

// ---------------------------------------------------------------------------
// Aggregation (bf16 rows, fp32 accumulate, bf16 out):
// y[v] = dinv[v] * ( sum_e dinv[src]*x[src] + dinv[v]*x[v] )
// Wave-per-node. F=256: uint2 (4 bf16)/lane. F=128: uint (2 bf16)/lane.
// ---------------------------------------------------------------------------
__global__ __launch_bounds__(256) void agg256_bf(const unsigned short* __restrict__ x,
    const unsigned long long* __restrict__ ent, const int* __restrict__ offs,
    const float* __restrict__ dinv, unsigned short* __restrict__ y, int n) {
  int v = (blockIdx.x * 256 + threadIdx.x) >> 6;
  int lane = threadIdx.x & 63;
  if (v >= n) return;
  float dv = dinv[v];
  const uint2* xv = (const uint2*)x;  // [N][64] uint2
  uint2 self = xv[(size_t)v * 64 + lane];
  float a0 = dv * blo(self.x), a1 = dv * bhi(self.x);
  float a2 = dv * blo(self.y), a3 = dv * bhi(self.y);
  int s = offs[v], e = offs[v + 1];
  int i = s;
  for (; i + 1 < e; i += 2) {
    unsigned long long p0 = ent[i], p1 = ent[i + 1];
    int s0 = (int)(p0 & 0xffffffffu), s1 = (int)(p1 & 0xffffffffu);
    float w0 = __int_as_float((int)(p0 >> 32));
    float w1 = __int_as_float((int)(p1 >> 32));
    uint2 r0 = xv[(size_t)s0 * 64 + lane];
    uint2 r1 = xv[(size_t)s1 * 64 + lane];
    a0 += w0 * blo(r0.x) + w1 * blo(r1.x);
    a1 += w0 * bhi(r0.x) + w1 * bhi(r1.x);
    a2 += w0 * blo(r0.y) + w1 * blo(r1.y);
    a3 += w0 * bhi(r0.y) + w1 * bhi(r1.y);
  }
  if (i < e) {
    unsigned long long p0 = ent[i];
    int s0 = (int)(p0 & 0xffffffffu);
    float w0 = __int_as_float((int)(p0 >> 32));
    uint2 r0 = xv[(size_t)s0 * 64 + lane];
    a0 += w0 * blo(r0.x); a1 += w0 * bhi(r0.x);
    a2 += w0 * blo(r0.y); a3 += w0 * bhi(r0.y);
  }
  ((uint2*)y)[(size_t)v * 64 + lane] =
      make_uint2(pack2(dv * a0, dv * a1), pack2(dv * a2, dv * a3));
}

__global__ __launch_bounds__(256) void agg128_bf(const unsigned short* __restrict__ x,
    const unsigned long long* __restrict__ ent, const int* __restrict__ offs,
    const float* __restrict__ dinv, unsigned short* __restrict__ y, int n) {
  int v = (blockIdx.x * 256 + threadIdx.x) >> 6;
  int lane = threadIdx.x & 63;
  if (v >= n) return;
  float dv = dinv[v];
  const unsigned* xv = (const unsigned*)x;  // [N][64] uint
  unsigned self = xv[(size_t)v * 64 + lane];
  float a0 = dv * blo(self), a1 = dv * bhi(self);
  int s = offs[v], e = offs[v + 1];
  int i = s;
  for (; i + 1 < e; i += 2) {
    unsigned long long p0 = ent[i], p1 = ent[i + 1];
    int s0 = (int)(p0 & 0xffffffffu), s1 = (int)(p1 & 0xffffffffu);
    float w0 = __int_as_float((int)(p0 >> 32));
    float w1 = __int_as_float((int)(p1 >> 32));
    unsigned r0 = xv[(size_t)s0 * 64 + lane];
    unsigned r1 = xv[(size_t)s1 * 64 + lane];
    a0 += w0 * blo(r0) + w1 * blo(r1);
    a1 += w0 * bhi(r0) + w1 * bhi(r1);
  }
  if (i < e) {
    unsigned long long p0 = ent[i];
    int s0 = (int)(p0 & 0xffffffffu);
    float w0 = __int_as_float((int)(p0 >> 32));
    unsigned r0 = xv[(size_t)s0 * 64 + lane];
    a0 += w0 * blo(r0); a1 += w0 * bhi(r0);
  }
  ((unsigned*)y)[(size_t)v * 64 + lane] = pack2(dv * a0, dv * a1);
}

// ---------------------------------------------------------------------------
// MFMA bf16 GEMM: C[M,256] = A[M,K]bf16 @ Wt[256,K]bf16^T + bias, opt ReLU,
// C stored bf16. 128x128 tile, BK=32, 256 thr = 4 waves (2x2), each wave
// 64x64 = 4x4 grid of 16x16x32 mfma. C/D layout: col=lane&15, row=quad*4+reg.
// ---------------------------------------------------------------------------
#define LDA 40  // 32 + 8 bf16 pad -> 80B row stride, keeps 16B align, ~2-way banks
__global__ __launch_bounds__(256) void gemm_mfma(
    const unsigned short* __restrict__ A, const unsigned short* __restrict__ Bt,
    const float* __restrict__ bias, unsigned short* __restrict__ C,
    int M, int K, int do_relu) {
  __shared__ unsigned short As[128 * LDA];
  __shared__ unsigned short Bs[128 * LDA];
  int tid = threadIdx.x;
  int row0 = blockIdx.x * 128;
  int col0 = blockIdx.y * 128;
  int wave = tid >> 6, lane = tid & 63;
  int wm = wave >> 1, wn = wave & 1;
  int lr = lane & 15, quad = lane >> 4;

  f32x4 acc[4][4];
#pragma unroll
  for (int i = 0; i < 4; ++i)
#pragma unroll
    for (int j = 0; j < 4; ++j) acc[i][j] = (f32x4){0.f, 0.f, 0.f, 0.f};

  for (int k0 = 0; k0 < K; k0 += 32) {
#pragma unroll
    for (int p = 0; p < 2; ++p) {
      int i = tid + p * 256;          // 0..511
      int r = i >> 2, q = i & 3;      // 128 rows x 4 16B-quads
      int row = row0 + r; if (row >= M) row = M - 1;
      uint4 va = *(const uint4*)(A + (size_t)row * K + k0 + q * 8);
      *(uint4*)&As[r * LDA + q * 8] = va;
      uint4 vb = *(const uint4*)(Bt + (size_t)(col0 + r) * K + k0 + q * 8);
      *(uint4*)&Bs[r * LDA + q * 8] = vb;
    }
    __syncthreads();
    bf16x8 af[4], bf[4];
#pragma unroll
    for (int mi = 0; mi < 4; ++mi)
      af[mi] = *(const bf16x8*)&As[(wm * 64 + mi * 16 + lr) * LDA + quad * 8];
#pragma unroll
    for (int ni = 0; ni < 4; ++ni)
      bf[ni] = *(const bf16x8*)&Bs[(wn * 64 + ni * 16 + lr) * LDA + quad * 8];
#pragma unroll
    for (int mi = 0; mi < 4; ++mi)
#pragma unroll
      for (int ni = 0; ni < 4; ++ni)
        acc[mi][ni] = __builtin_amdgcn_mfma_f32_16x16x32_bf16(af[mi], bf[ni], acc[mi][ni], 0, 0, 0);
    __syncthreads();
  }

  // epilogue: bias + optional relu, store bf16
  float bv[4];
#pragma unroll
  for (int ni = 0; ni < 4; ++ni) bv[ni] = bias[col0 + wn * 64 + ni * 16 + lr];
#pragma unroll
  for (int mi = 0; mi < 4; ++mi) {
#pragma unroll
    for (int r = 0; r < 4; ++r) {
      int grow = row0 + wm * 64 + mi * 16 + quad * 4 + r;
      if (grow < M) {
#pragma unroll
        for (int ni = 0; ni < 4; ++ni) {
          float v = acc[mi][ni][r] + bv[ni];
          if (do_relu) v = fmaxf(v, 0.f);
          C[(size_t)grow * 256 + col0 + wn * 64 + ni * 16 + lr] = f2b(v);
        }
      }
    }
  }
}

// ---------------------------------------------------------------------------
// Pooling: batch is sorted; per-block run-length accumulate then atomicAdd.
// Counting fused (thread f==0 adds run length once per run).
// ---------------------------------------------------------------------------
__global__ __launch_bounds__(256) void pool_sum_bf(const unsigned short* __restrict__ h,
    const int* __restrict__ batch, float* __restrict__ sums,
    float* __restrict__ cnts, int n) {
  int f = threadIdx.x;           // 0..255 feature
  int v0 = blockIdx.x * 128;
  if (v0 >= n) return;
  int vend = min(v0 + 128, n);
  int cur = batch[v0];
  float acc = 0.f;
  int cnt = 0;
  for (int v = v0; v < vend; ++v) {
    int b = batch[v];
    if (b != cur) {
      atomicAdd(&sums[cur * 256 + f], acc);
      if (f == 0) atomicAdd(&cnts[cur], (float)cnt);
      acc = 0.f; cnt = 0; cur = b;
    }
    acc += b2f(h[(size_t)v * 256 + f]);
    cnt++;
  }
  atomicAdd(&sums[cur * 256 + f], acc);
  if (f == 0) atomicAdd(&cnts[cur], (float)cnt);
}

// z[g,f] = (sums[g,:]/max(cnt,1)) @ lin0_W[:,f] + lin0_b[f]   (64 blocks x 128 thr)
__global__ __launch_bounds__(128) void pool_lin(const float* __restrict__ sums,
    const float* __restrict__ cnts, const float* __restrict__ W128,
    const float* __restrict__ b128, float* __restrict__ z) {
  int g = blockIdx.x, f = threadIdx.x;
  float inv = 1.0f / fmaxf(cnts[g], 1.0f);
  float acc = 0.f;
  for (int k = 0; k < 256; ++k)
    acc += (sums[g * 256 + k] * inv) * W128[k * 128 + f];
  z[g * 128 + f] = acc + b128[f];
}

// ---------------------------------------------------------------------------
// Final triplet outputs. out layout: z0[8192] z1[8192] z2[8192] correct[1]
// score_p[64] score_n[64] correct_score[1]
// ---------------------------------------------------------------------------
__global__ __launch_bounds__(64) void final_triplet(const float* __restrict__ z,
    const float* __restrict__ lin_W, const float* __restrict__ lin_b,
    float* __restrict__ out) {
  int g = threadIdx.x;  // 0..63, one wave
  const float* z0 = z;
  const float* z1 = z + 8192;
  const float* z2 = z + 16384;
  float dp = 0.f, dn = 0.f;
  float y1 = lin_b[0], y2 = lin_b[0];
  for (int f = 0; f < 128; ++f) {
    float a = z0[g * 128 + f], b = z1[g * 128 + f], c = z2[g * 128 + f];
    float d1 = a - b + 1e-6f, d2 = a - c + 1e-6f;
    dp += d1 * d1; dn += d2 * d2;
    float w0 = lin_W[f], w1 = lin_W[128 + f];
    y1 += a * w0 + b * w1;
    y2 += a * w0 + c * w1;
  }
  dp = sqrtf(dp); dn = sqrtf(dn);
  float sp = 1.f / (1.f + expf(-y1));
  float sn = 1.f / (1.f + expf(-y2));
  out[24577 + g] = sp;
  out[24641 + g] = sn;
  unsigned long long m1 = __ballot(dn - dp > 0.f);
  unsigned long long m2 = __ballot(sp - sn > 0.f);
  if (g == 0) {
    out[24576] = (float)__popcll(m1);
    out[24705] = (float)__popcll(m2);
  }
}

// ---------------------------------------------------------------------------
extern "C" void kernel_launch(void* const* d_in, const int* in_sizes, int n_in,
                              void* d_out, int out_size, void* d_ws, size_t ws_size,
                              hipStream_t stream) {
  const float* xin[3]  = {(const float*)d_in[0], (const float*)d_in[1], (const float*)d_in[2]};
  const int* ei[3]     = {(const int*)d_in[3], (const int*)d_in[4], (const int*)d_in[5]};
  const int* batch[3]  = {(const int*)d_in[6], (const int*)d_in[7], (const int*)d_in[8]};
  const float* W0 = (const float*)d_in[9],  *b0 = (const float*)d_in[10];
  const float* W1 = (const float*)d_in[11], *b1 = (const float*)d_in[12];
  const float* W2 = (const float*)d_in[13], *b2 = (const float*)d_in[14];
  const float* lin0W = (const float*)d_in[15], *lin0b = (const float*)d_in[16];
  const float* linW  = (const float*)d_in[17], *linb  = (const float*)d_in[18];
  float* out = (float*)d_out;

  // workspace carve (16B-aligned by construction)
  unsigned short* ybf = (unsigned short*)d_ws;        // N*256 bf16 = 51.2 MB
  unsigned short* hbf = ybf + (size_t)NN * 256;       // N*256 bf16 = 51.2 MB
  unsigned short* xbf = hbf + (size_t)NN * 256;       // N*128 bf16 = 25.6 MB
  unsigned long long* ent = (unsigned long long*)(xbf + (size_t)NN * 128);  // E*8B
  unsigned short* Wt0 = (unsigned short*)(ent + EE);  // 256*128
  unsigned short* Wt1 = Wt0 + 256 * 128;              // 256*256
  unsigned short* Wt2 = Wt1 + 256 * 256;              // 256*256
  int* deg   = (int*)(Wt2 + 256 * 256);               // N ints -- zeroed region start
  int* fillc = deg + NN;                              // N ints
  float* sums = (float*)(fillc + NN);                 // 64*256 floats
  float* cnts = sums + 64 * 256;                      // 64 floats
  int zero_elems = NN + NN + 64 * 256 + 64;           // deg..cnts contiguous
  float* dinv = cnts + 64;                            // N floats
  int* offs = (int*)(dinv + NN);                      // N+1 ints

  const int EB = (EE + 255) / 256;
  const int NB = (NN + 255) / 256;
  dim3 ggrid((NN + 127) / 128, 2);

  // weight conversion (once per launch)
  conv_wt<<<(256 * 128 + 255) / 256, 256, 0, stream>>>(W0, Wt0, 128);
  conv_wt<<<(256 * 256 + 255) / 256, 256, 0, stream>>>(W1, Wt1, 256);
  conv_wt<<<(256 * 256 + 255) / 256, 256, 0, stream>>>(W2, Wt2, 256);

  for (int g = 0; g < 3; ++g) {
    const int* src = ei[g];
    const int* dst = ei[g] + EE;
    zero_int<<<(zero_elems + 255) / 256, 256, 0, stream>>>(deg, zero_elems);
    hist_deg<<<EB, 256, 0, stream>>>(dst, deg, EE);
    calc_dinv<<<NB, 256, 0, stream>>>(deg, dinv, NN);
    scan_excl<<<1, 1024, 0, stream>>>(deg, offs, NN);
    fill_csr<<<EB, 256, 0, stream>>>(src, dst, dinv, offs, fillc, ent, EE);

    // convert input features to bf16
    conv_bf<<<(NN * 128 / 4 + 255) / 256, 256, 0, stream>>>(xin[g], (unsigned*)xbf, NN * 128 / 4);

    // layer 0: aggregate (F=128) then MFMA GEMM K=128 -> h (ReLU)
    agg128_bf<<<(NN + 3) / 4, 256, 0, stream>>>(xbf, ent, offs, dinv, ybf, NN);
    gemm_mfma<<<ggrid, 256, 0, stream>>>(ybf, Wt0, b0, hbf, NN, 128, 1);
    // layer 1
    agg256_bf<<<(NN + 3) / 4, 256, 0, stream>>>(hbf, ent, offs, dinv, ybf, NN);
    gemm_mfma<<<ggrid, 256, 0, stream>>>(ybf, Wt1, b1, hbf, NN, 256, 1);
    // layer 2 (no relu)
    agg256_bf<<<(NN + 3) / 4, 256, 0, stream>>>(hbf, ent, offs, dinv, ybf, NN);
    gemm_mfma<<<ggrid, 256, 0, stream>>>(ybf, Wt2, b2, hbf, NN, 256, 0);

    // pool (+fused count) + lin0 -> z_g written directly into d_out
    pool_sum_bf<<<(NN + 127) / 128, 256, 0, stream>>>(hbf, batch[g], sums, cnts, NN);
    pool_lin<<<64, 128, 0, stream>>>(sums, cnts, lin0W, lin0b, out + g * 8192);
  }

  final_triplet<<<1, 64, 0, stream>>>(out, linW, linb, out);
}

// Round 5
// 3352.447 us; speedup vs baseline: 2.4541x; 1.1450x over previous
//
#include <hip/hip_runtime.h>
#include <math.h>

// Problem constants (match reference setup_inputs)
#define NN 100000
#define EE 3200000
// H = 256, F_IN = 128, G = 64

typedef __attribute__((ext_vector_type(8))) short bf16x8;
typedef __attribute__((ext_vector_type(4))) float f32x4;

// fp32 -> bf16 (round to nearest even), raw ushort
__device__ __forceinline__ unsigned short f2b(float f) {
  unsigned u = __float_as_uint(f);
  u += 0x7fffu + ((u >> 16) & 1u);
  return (unsigned short)(u >> 16);
}
// bf16 (raw ushort) -> fp32
__device__ __forceinline__ float b2f(unsigned short s) {
  return __uint_as_float(((unsigned)s) << 16);
}
__device__ __forceinline__ float blo(unsigned u) { return __uint_as_float(u << 16); }
__device__ __forceinline__ float bhi(unsigned u) { return __uint_as_float(u & 0xffff0000u); }
__device__ __forceinline__ unsigned pack2(float lo, float hi) {
  return ((unsigned)f2b(hi) << 16) | (unsigned)f2b(lo);
}

// ---------------------------------------------------------------------------
// Batched CSR prep across the 3 graphs
// ---------------------------------------------------------------------------
__global__ void zero_int(int* __restrict__ p, int n) {
  int i = blockIdx.x * 256 + threadIdx.x;
  if (i < n) p[i] = 0;
}

// grid (EB, 3): blockIdx.y selects graph's dst array; deg3 is [3][N]
__global__ void hist_deg3(const int* __restrict__ d0, const int* __restrict__ d1,
                          const int* __restrict__ d2, int* __restrict__ deg3, int e) {
  int i = blockIdx.x * 256 + threadIdx.x;
  if (i >= e) return;
  const int* dst = (blockIdx.y == 0) ? d0 : (blockIdx.y == 1) ? d1 : d2;
  atomicAdd(&deg3[blockIdx.y * NN + dst[i]], 1);
}

__global__ void calc_dinv3(const int* __restrict__ deg3, float* __restrict__ dinv3, int n3) {
  int i = blockIdx.x * 256 + threadIdx.x;
  if (i < n3) dinv3[i] = 1.0f / sqrtf((float)(deg3[i] + 1));
}

// 3 blocks, one per graph. Exclusive scan of deg3[g] -> offs3[g] (len N+1).
__global__ __launch_bounds__(1024) void scan_excl3(const int* __restrict__ deg3,
                                                   int* __restrict__ offs3, int n) {
  const int* deg = deg3 + blockIdx.x * NN;
  int* offs = offs3 + blockIdx.x * (NN + 1);
  __shared__ int wsum[16];
  __shared__ int s_carry;
  int tid = threadIdx.x;
  int lane = tid & 63, wv = tid >> 6;
  if (tid == 0) s_carry = 0;
  __syncthreads();
  for (int base = 0; base < n; base += 1024) {
    int idx = base + tid;
    int v = (idx < n) ? deg[idx] : 0;
    int x = v;
#pragma unroll
    for (int o = 1; o < 64; o <<= 1) {
      int t = __shfl_up(x, o, 64);
      if (lane >= o) x += t;
    }
    if (lane == 63) wsum[wv] = x;
    __syncthreads();
    int carry = s_carry;
    int woff = 0;
    for (int j = 0; j < wv; ++j) woff += wsum[j];
    if (idx < n) offs[idx] = carry + woff + x - v;
    __syncthreads();
    if (tid == 1023) s_carry = carry + woff + x;  // carry + chunk total
    __syncthreads();
  }
  if (threadIdx.x == 0) offs[n] = s_carry;
}

__global__ void fill_csr(const int* __restrict__ src, const int* __restrict__ dst,
                         const float* __restrict__ dinv, const int* __restrict__ offs,
                         int* __restrict__ fillc, unsigned long long* __restrict__ ent,
                         int e) {
  int i = blockIdx.x * 256 + threadIdx.x;
  if (i >= e) return;
  int d = dst[i], s = src[i];
  int pos = offs[d] + atomicAdd(&fillc[d], 1);
  unsigned long long w = (unsigned long long)(unsigned)__float_as_int(dinv[s]);
  ent[pos] = (w << 32) | (unsigned)s;
}

// ---------------------------------------------------------------------------
// dtype converters
// ---------------------------------------------------------------------------
__global__ void conv_bf(const float* __restrict__ in, unsigned* __restrict__ out, int n4) {
  int i = blockIdx.x * 256 + threadIdx.x;
  if (i >= n4) return;
  float4 v = ((const float4*)in)[i];
  ((uint2*)out)[i] = make_uint2(pack2(v.x, v.y), pack2(v.z, v.w));
}

// W[K][256] fp32 -> Wt[256][K] bf16 (transposed for gemm B^T operand)
__global__ void conv_wt(const float* __restrict__ W, unsigned short* __restrict__ Wt, int K) {
  int i = blockIdx.x * 256 + threadIdx.x;
  if (i >= 256 * K) return;
  int nn = i / K, kk = i - nn * K;
  Wt[i] = f2b(W[(size_t)kk * 256 + nn]);
}

// ---------------------------------------------------------------------------
// Aggregation (bf16 rows, fp32 accumulate, bf16 out):
// y[v] = dinv[v] * ( sum_e dinv[src]*x[src] + dinv[v]*x[v] )
// Wave-per-node, v made wave-uniform via readfirstlane so ent/offs become
// scalar s_loads; row address = scalar base + invariant lane offset (zero
// per-edge vector address math); weight rides the SGPR operand of v_fmac.
// 4-edge unroll for 4 gathers in flight.
// ---------------------------------------------------------------------------
__global__ __launch_bounds__(256) void agg256_bf(const unsigned short* __restrict__ x,
    const unsigned long long* __restrict__ ent, const int* __restrict__ offs,
    const float* __restrict__ dinv, unsigned short* __restrict__ y, int n) {
  int v = (blockIdx.x * 256 + threadIdx.x) >> 6;
  v = __builtin_amdgcn_readfirstlane(v);
  int lane = threadIdx.x & 63;
  if (v >= n) return;
  float dv = dinv[v];
  const uint2* selfp = (const uint2*)(x + ((size_t)(unsigned)v << 8)) + lane;
  uint2 self = *selfp;
  float a0 = dv * blo(self.x), a1 = dv * bhi(self.x);
  float a2 = dv * blo(self.y), a3 = dv * bhi(self.y);
  int s = offs[v], e = offs[v + 1];
  int i = s;
  for (; i + 3 < e; i += 4) {
    unsigned long long p0 = ent[i], p1 = ent[i + 1], p2 = ent[i + 2], p3 = ent[i + 3];
    unsigned s0 = (unsigned)p0, s1 = (unsigned)p1, s2 = (unsigned)p2, s3 = (unsigned)p3;
    float w0 = __uint_as_float((unsigned)(p0 >> 32));
    float w1 = __uint_as_float((unsigned)(p1 >> 32));
    float w2 = __uint_as_float((unsigned)(p2 >> 32));
    float w3 = __uint_as_float((unsigned)(p3 >> 32));
    uint2 r0 = *((const uint2*)(x + ((size_t)s0 << 8)) + lane);
    uint2 r1 = *((const uint2*)(x + ((size_t)s1 << 8)) + lane);
    uint2 r2 = *((const uint2*)(x + ((size_t)s2 << 8)) + lane);
    uint2 r3 = *((const uint2*)(x + ((size_t)s3 << 8)) + lane);
    a0 += w0 * blo(r0.x); a1 += w0 * bhi(r0.x); a2 += w0 * blo(r0.y); a3 += w0 * bhi(r0.y);
    a0 += w1 * blo(r1.x); a1 += w1 * bhi(r1.x); a2 += w1 * blo(r1.y); a3 += w1 * bhi(r1.y);
    a0 += w2 * blo(r2.x); a1 += w2 * bhi(r2.x); a2 += w2 * blo(r2.y); a3 += w2 * bhi(r2.y);
    a0 += w3 * blo(r3.x); a1 += w3 * bhi(r3.x); a2 += w3 * blo(r3.y); a3 += w3 * bhi(r3.y);
  }
  for (; i < e; ++i) {
    unsigned long long p0 = ent[i];
    unsigned s0 = (unsigned)p0;
    float w0 = __uint_as_float((unsigned)(p0 >> 32));
    uint2 r0 = *((const uint2*)(x + ((size_t)s0 << 8)) + lane);
    a0 += w0 * blo(r0.x); a1 += w0 * bhi(r0.x); a2 += w0 * blo(r0.y); a3 += w0 * bhi(r0.y);
  }
  uint2* yp = (uint2*)(y + ((size_t)(unsigned)v << 8)) + lane;
  *yp = make_uint2(pack2(dv * a0, dv * a1), pack2(dv * a2, dv * a3));
}

__global__ __launch_bounds__(256) void agg128_bf(const unsigned short* __restrict__ x,
    const unsigned long long* __restrict__ ent, const int* __restrict__ offs,
    const float* __restrict__ dinv, unsigned short* __restrict__ y, int n) {
  int v = (blockIdx.x * 256 + threadIdx.x) >> 6;
  v = __builtin_amdgcn_readfirstlane(v);
  int lane = threadIdx.x & 63;
  if (v >= n) return;
  float dv = dinv[v];
  const unsigned* selfp = (const unsigned*)(x + ((size_t)(unsigned)v << 7)) + lane;
  unsigned self = *selfp;
  float a0 = dv * blo(self), a1 = dv * bhi(self);
  int s = offs[v], e = offs[v + 1];
  int i = s;
  for (; i + 3 < e; i += 4) {
    unsigned long long p0 = ent[i], p1 = ent[i + 1], p2 = ent[i + 2], p3 = ent[i + 3];
    unsigned s0 = (unsigned)p0, s1 = (unsigned)p1, s2 = (unsigned)p2, s3 = (unsigned)p3;
    float w0 = __uint_as_float((unsigned)(p0 >> 32));
    float w1 = __uint_as_float((unsigned)(p1 >> 32));
    float w2 = __uint_as_float((unsigned)(p2 >> 32));
    float w3 = __uint_as_float((unsigned)(p3 >> 32));
    unsigned r0 = *((const unsigned*)(x + ((size_t)s0 << 7)) + lane);
    unsigned r1 = *((const unsigned*)(x + ((size_t)s1 << 7)) + lane);
    unsigned r2 = *((const unsigned*)(x + ((size_t)s2 << 7)) + lane);
    unsigned r3 = *((const unsigned*)(x + ((size_t)s3 << 7)) + lane);
    a0 += w0 * blo(r0); a1 += w0 * bhi(r0);
    a0 += w1 * blo(r1); a1 += w1 * bhi(r1);
    a0 += w2 * blo(r2); a1 += w2 * bhi(r2);
    a0 += w3 * blo(r3); a1 += w3 * bhi(r3);
  }
  for (; i < e; ++i) {
    unsigned long long p0 = ent[i];
    unsigned s0 = (unsigned)p0;
    float w0 = __uint_as_float((unsigned)(p0 >> 32));
    unsigned r0 = *((const unsigned*)(x + ((size_t)s0 << 7)) + lane);
    a0 += w0 * blo(r0); a1 += w0 * bhi(r0);
  }
  unsigned* yp = (unsigned*)(y + ((size_t)(unsigned)v << 7)) + lane;
  *yp = pack2(dv * a0, dv * a1);
}

// ---------------------------------------------------------------------------
// MFMA bf16 GEMM: C[M,256] = A[M,K]bf16 @ Wt[256,K]bf16^T + bias, opt ReLU,
// C stored bf16. 128x128 tile, BK=32, 256 thr = 4 waves (2x2), each wave
// 64x64 = 4x4 grid of 16x16x32 mfma. C/D layout: col=lane&15, row=quad*4+reg.
// ---------------------------------------------------------------------------
#define LDA 40  // 32 + 8 bf16 pad -> 80B row stride, keeps 16B align
__global__ __launch_bounds__(256) void gemm_mfma(
    const unsigned short* __restrict__ A, const unsigned short* __restrict__ Bt,
    const float* __restrict__ bias, unsigned short* __restrict__ C,
    int M, int K, int do_relu) {
  __shared__ unsigned short As[128 * LDA];
  __shared__ unsigned short Bs[128 * LDA];
  int tid = threadIdx.x;
  int row0 = blockIdx.x * 128;
  int col0 = blockIdx.y * 128;
  int wave = tid >> 6, lane = tid & 63;
  int wm = wave >> 1, wn = wave & 1;
  int lr = lane & 15, quad = lane >> 4;

  f32x4 acc[4][4];
#pragma unroll
  for (int i = 0; i < 4; ++i)
#pragma unroll
    for (int j = 0; j < 4; ++j) acc[i][j] = (f32x4){0.f, 0.f, 0.f, 0.f};

  for (int k0 = 0; k0 < K; k0 += 32) {
#pragma unroll
    for (int p = 0; p < 2; ++p) {
      int i = tid + p * 256;          // 0..511
      int r = i >> 2, q = i & 3;      // 128 rows x 4 16B-quads
      int row = row0 + r; if (row >= M) row = M - 1;
      uint4 va = *(const uint4*)(A + (size_t)row * K + k0 + q * 8);
      *(uint4*)&As[r * LDA + q * 8] = va;
      uint4 vb = *(const uint4*)(Bt + (size_t)(col0 + r) * K + k0 + q * 8);
      *(uint4*)&Bs[r * LDA + q * 8] = vb;
    }
    __syncthreads();
    bf16x8 af[4], bf[4];
#pragma unroll
    for (int mi = 0; mi < 4; ++mi)
      af[mi] = *(const bf16x8*)&As[(wm * 64 + mi * 16 + lr) * LDA + quad * 8];
#pragma unroll
    for (int ni = 0; ni < 4; ++ni)
      bf[ni] = *(const bf16x8*)&Bs[(wn * 64 + ni * 16 + lr) * LDA + quad * 8];
#pragma unroll
    for (int mi = 0; mi < 4; ++mi)
#pragma unroll
      for (int ni = 0; ni < 4; ++ni)
        acc[mi][ni] = __builtin_amdgcn_mfma_f32_16x16x32_bf16(af[mi], bf[ni], acc[mi][ni], 0, 0, 0);
    __syncthreads();
  }

  // epilogue: bias + optional relu, store bf16
  float bv[4];
#pragma unroll
  for (int ni = 0; ni < 4; ++ni) bv[ni] = bias[col0 + wn * 64 + ni * 16 + lr];
#pragma unroll
  for (int mi = 0; mi < 4; ++mi) {
#pragma unroll
    for (int r = 0; r < 4; ++r) {
      int grow = row0 + wm * 64 + mi * 16 + quad * 4 + r;
      if (grow < M) {
#pragma unroll
        for (int ni = 0; ni < 4; ++ni) {
          float v = acc[mi][ni][r] + bv[ni];
          if (do_relu) v = fmaxf(v, 0.f);
          C[(size_t)grow * 256 + col0 + wn * 64 + ni * 16 + lr] = f2b(v);
        }
      }
    }
  }
}

// ---------------------------------------------------------------------------
// Pooling: batch is sorted; per-block run-length accumulate then atomicAdd.
// Counting fused (thread f==0 adds run length once per run).
// ---------------------------------------------------------------------------
__global__ __launch_bounds__(256) void pool_sum_bf(const unsigned short* __restrict__ h,
    const int* __restrict__ batch, float* __restrict__ sums,
    float* __restrict__ cnts, int n) {
  int f = threadIdx.x;           // 0..255 feature
  int v0 = blockIdx.x * 128;
  if (v0 >= n) return;
  int vend = min(v0 + 128, n);
  int cur = batch[v0];
  float acc = 0.f;
  int cnt = 0;
  for (int v = v0; v < vend; ++v) {
    int b = batch[v];
    if (b != cur) {
      atomicAdd(&sums[cur * 256 + f], acc);
      if (f == 0) atomicAdd(&cnts[cur], (float)cnt);
      acc = 0.f; cnt = 0; cur = b;
    }
    acc += b2f(h[(size_t)v * 256 + f]);
    cnt++;
  }
  atomicAdd(&sums[cur * 256 + f], acc);
  if (f == 0) atomicAdd(&cnts[cur], (float)cnt);
}

// z[g,f] = (sums[g,:]/max(cnt,1)) @ lin0_W[:,f] + lin0_b[f]   (64 blocks x 128 thr)
__global__ __launch_bounds__(128) void pool_lin(const float* __restrict__ sums,
    const float* __restrict__ cnts, const float* __restrict__ W128,
    const float* __restrict__ b128, float* __restrict__ z) {
  int g = blockIdx.x, f = threadIdx.x;
  float inv = 1.0f / fmaxf(cnts[g], 1.0f);
  float acc = 0.f;
  for (int k = 0; k < 256; ++k)
    acc += (sums[g * 256 + k] * inv) * W128[k * 128 + f];
  z[g * 128 + f] = acc + b128[f];
}

// ---------------------------------------------------------------------------
// Final triplet outputs. out layout: z0[8192] z1[8192] z2[8192] correct[1]
// score_p[64] score_n[64] correct_score[1]
// ---------------------------------------------------------------------------
__global__ __launch_bounds__(64) void final_triplet(const float* __restrict__ z,
    const float* __restrict__ lin_W, const float* __restrict__ lin_b,
    float* __restrict__ out) {
  int g = threadIdx.x;  // 0..63, one wave
  const float* z0 = z;
  const float* z1 = z + 8192;
  const float* z2 = z + 16384;
  float dp = 0.f, dn = 0.f;
  float y1 = lin_b[0], y2 = lin_b[0];
  for (int f = 0; f < 128; ++f) {
    float a = z0[g * 128 + f], b = z1[g * 128 + f], c = z2[g * 128 + f];
    float d1 = a - b + 1e-6f, d2 = a - c + 1e-6f;
    dp += d1 * d1; dn += d2 * d2;
    float w0 = lin_W[f], w1 = lin_W[128 + f];
    y1 += a * w0 + b * w1;
    y2 += a * w0 + c * w1;
  }
  dp = sqrtf(dp); dn = sqrtf(dn);
  float sp = 1.f / (1.f + expf(-y1));
  float sn = 1.f / (1.f + expf(-y2));
  out[24577 + g] = sp;
  out[24641 + g] = sn;
  unsigned long long m1 = __ballot(dn - dp > 0.f);
  unsigned long long m2 = __ballot(sp - sn > 0.f);
  if (g == 0) {
    out[24576] = (float)__popcll(m1);
    out[24705] = (float)__popcll(m2);
  }
}

// ---------------------------------------------------------------------------
extern "C" void kernel_launch(void* const* d_in, const int* in_sizes, int n_in,
                              void* d_out, int out_size, void* d_ws, size_t ws_size,
                              hipStream_t stream) {
  const float* xin[3]  = {(const float*)d_in[0], (const float*)d_in[1], (const float*)d_in[2]};
  const int* ei[3]     = {(const int*)d_in[3], (const int*)d_in[4], (const int*)d_in[5]};
  const int* batch[3]  = {(const int*)d_in[6], (const int*)d_in[7], (const int*)d_in[8]};
  const float* W0 = (const float*)d_in[9],  *b0 = (const float*)d_in[10];
  const float* W1 = (const float*)d_in[11], *b1 = (const float*)d_in[12];
  const float* W2 = (const float*)d_in[13], *b2 = (const float*)d_in[14];
  const float* lin0W = (const float*)d_in[15], *lin0b = (const float*)d_in[16];
  const float* linW  = (const float*)d_in[17], *linb  = (const float*)d_in[18];
  float* out = (float*)d_out;

  // workspace carve (16B-aligned by construction)
  unsigned short* ybf = (unsigned short*)d_ws;        // N*256 bf16 = 51.2 MB
  unsigned short* hbf = ybf + (size_t)NN * 256;       // N*256 bf16 = 51.2 MB
  unsigned short* xbf = hbf + (size_t)NN * 256;       // N*128 bf16 = 25.6 MB
  unsigned long long* ent = (unsigned long long*)(xbf + (size_t)NN * 128);  // E*8B
  unsigned short* Wt0 = (unsigned short*)(ent + EE);  // 256*128
  unsigned short* Wt1 = Wt0 + 256 * 128;              // 256*256
  unsigned short* Wt2 = Wt1 + 256 * 256;              // 256*256
  // zeroed region: deg3, fillc3, sums3, cnts3 (contiguous)
  int* deg3   = (int*)(Wt2 + 256 * 256);              // 3N ints
  int* fillc3 = deg3 + 3 * NN;                        // 3N ints
  float* sums3 = (float*)(fillc3 + 3 * NN);           // 3*64*256 floats
  float* cnts3 = sums3 + 3 * 64 * 256;                // 3*64 floats
  int zero_elems = 3 * NN + 3 * NN + 3 * 64 * 256 + 3 * 64;
  float* dinv3 = cnts3 + 3 * 64;                      // 3N floats
  int* offs3 = (int*)(dinv3 + 3 * NN);                // 3*(N+1) ints

  const int EB = (EE + 255) / 256;
  dim3 ggrid((NN + 127) / 128, 2);

  // weight conversion (once per launch)
  conv_wt<<<(256 * 128 + 255) / 256, 256, 0, stream>>>(W0, Wt0, 128);
  conv_wt<<<(256 * 256 + 255) / 256, 256, 0, stream>>>(W1, Wt1, 256);
  conv_wt<<<(256 * 256 + 255) / 256, 256, 0, stream>>>(W2, Wt2, 256);

  // batched CSR prep for all 3 graphs
  zero_int<<<(zero_elems + 255) / 256, 256, 0, stream>>>(deg3, zero_elems);
  hist_deg3<<<dim3(EB, 3), 256, 0, stream>>>(ei[0] + EE, ei[1] + EE, ei[2] + EE, deg3, EE);
  calc_dinv3<<<(3 * NN + 255) / 256, 256, 0, stream>>>(deg3, dinv3, 3 * NN);
  scan_excl3<<<3, 1024, 0, stream>>>(deg3, offs3, NN);

  for (int g = 0; g < 3; ++g) {
    const int* src = ei[g];
    const int* dst = ei[g] + EE;
    const float* dinv = dinv3 + (size_t)g * NN;
    const int* offs = offs3 + (size_t)g * (NN + 1);

    fill_csr<<<EB, 256, 0, stream>>>(src, dst, dinv, offs, fillc3 + (size_t)g * NN, ent, EE);

    // convert input features to bf16
    conv_bf<<<(NN * 128 / 4 + 255) / 256, 256, 0, stream>>>(xin[g], (unsigned*)xbf, NN * 128 / 4);

    // layer 0: aggregate (F=128) then MFMA GEMM K=128 -> h (ReLU)
    agg128_bf<<<(NN + 3) / 4, 256, 0, stream>>>(xbf, ent, offs, dinv, ybf, NN);
    gemm_mfma<<<ggrid, 256, 0, stream>>>(ybf, Wt0, b0, hbf, NN, 128, 1);
    // layer 1
    agg256_bf<<<(NN + 3) / 4, 256, 0, stream>>>(hbf, ent, offs, dinv, ybf, NN);
    gemm_mfma<<<ggrid, 256, 0, stream>>>(ybf, Wt1, b1, hbf, NN, 256, 1);
    // layer 2 (no relu)
    agg256_bf<<<(NN + 3) / 4, 256, 0, stream>>>(hbf, ent, offs, dinv, ybf, NN);
    gemm_mfma<<<ggrid, 256, 0, stream>>>(ybf, Wt2, b2, hbf, NN, 256, 0);

    // pool (+fused count) + lin0 -> z_g written directly into d_out
    pool_sum_bf<<<(NN + 127) / 128, 256, 0, stream>>>(hbf, batch[g],
        sums3 + (size_t)g * 64 * 256, cnts3 + (size_t)g * 64, NN);
    pool_lin<<<64, 128, 0, stream>>>(sums3 + (size_t)g * 64 * 256, cnts3 + (size_t)g * 64,
        lin0W, lin0b, out + g * 8192);
  }

  final_triplet<<<1, 64, 0, stream>>>(out, linW, linb, out);
}

// Round 6
// 3236.552 us; speedup vs baseline: 2.5420x; 1.0358x over previous
//
#include <hip/hip_runtime.h>
#include <math.h>

// Problem constants (match reference setup_inputs)
#define NN 100000
#define EE 3200000
// H = 256, F_IN = 128, G = 64

typedef __attribute__((ext_vector_type(8))) short bf16x8;
typedef __attribute__((ext_vector_type(4))) float f32x4;

// fp32 -> bf16 (round to nearest even), raw ushort
__device__ __forceinline__ unsigned short f2b(float f) {
  unsigned u = __float_as_uint(f);
  u += 0x7fffu + ((u >> 16) & 1u);
  return (unsigned short)(u >> 16);
}
// bf16 (raw ushort) -> fp32
__device__ __forceinline__ float b2f(unsigned short s) {
  return __uint_as_float(((unsigned)s) << 16);
}
__device__ __forceinline__ float blo(unsigned u) { return __uint_as_float(u << 16); }
__device__ __forceinline__ float bhi(unsigned u) { return __uint_as_float(u & 0xffff0000u); }
__device__ __forceinline__ unsigned pack2(float lo, float hi) {
  return ((unsigned)f2b(hi) << 16) | (unsigned)f2b(lo);
}

// ---------------------------------------------------------------------------
// Degree histogram: LDS-privatized multi-pass, ZERO global atomics.
// Packed 2x ushort counters (max degree ~60 << 65535 so no carry).
// ---------------------------------------------------------------------------
#define WPB 8192            // LDS words per block (32 KB) = 16384 packed counters
#define NODES_PER_PASS 16384
#define NPASS 7             // 7*16384 = 114688 >= NN
#define HB 16               // blocks per (pass, graph); EE % HB == 0

__global__ void zero_int(int* __restrict__ p, int n) {
  int i = blockIdx.x * 256 + threadIdx.x;
  if (i < n) p[i] = 0;
}

// grid (HB, NPASS, 3). partials[( (g*NPASS+p)*HB + b )][WPB]
__global__ __launch_bounds__(256) void hist_part(
    const int* __restrict__ d0, const int* __restrict__ d1, const int* __restrict__ d2,
    unsigned* __restrict__ partials) {
  __shared__ unsigned cnt[WPB];
  int b = blockIdx.x, p = blockIdx.y, g = blockIdx.z;
  const int* dst = (g == 0) ? d0 : (g == 1) ? d1 : d2;
  for (int i = threadIdx.x; i < WPB; i += 256) cnt[i] = 0;
  __syncthreads();
  unsigned lo = (unsigned)(p * NODES_PER_PASS);
  int base = b * (EE / HB);
  int end = base + EE / HB;
  for (int i = base + threadIdx.x; i < end; i += 256) {
    unsigned n = (unsigned)dst[i] - lo;
    if (n < NODES_PER_PASS)
      atomicAdd(&cnt[n >> 1], 1u << ((n & 1) * 16));
  }
  __syncthreads();
  unsigned* out = partials + ((size_t)((g * NPASS + p) * HB + b)) * WPB;
  for (int i = threadIdx.x; i < WPB; i += 256) out[i] = cnt[i];
}

// grid (WPB/256, NPASS, 3): sum HB partials -> packed deg words (plain store).
__global__ void hist_reduce(const unsigned* __restrict__ partials,
                            unsigned* __restrict__ deg3w) {
  int i = blockIdx.x * 256 + threadIdx.x;  // word within (g,p)
  int p = blockIdx.y, g = blockIdx.z;
  unsigned s = 0;
  const unsigned* base = partials + ((size_t)((g * NPASS + p) * HB)) * WPB + i;
#pragma unroll
  for (int b = 0; b < HB; ++b) s += base[(size_t)b * WPB];
  int word = p * WPB + i;                  // word within graph (node = 2*word)
  if (word < NN / 2) deg3w[(size_t)g * (NN / 2) + word] = s;
}

__global__ void calc_dinv3(const unsigned short* __restrict__ deg3u,
                           float* __restrict__ dinv3, int n3) {
  int i = blockIdx.x * 256 + threadIdx.x;
  if (i < n3) dinv3[i] = 1.0f / sqrtf((float)(deg3u[i] + 1));
}

// ---------------------------------------------------------------------------
// Hierarchical exclusive scan of ushort degrees -> int offs (per graph)
// ---------------------------------------------------------------------------
#define SCHUNK 1024
#define NCHUNK 98   // 98*1024 = 100352 >= NN

// grid (NCHUNK, 3), block 256: chunk sums
__global__ __launch_bounds__(256) void scan_part(const unsigned short* __restrict__ deg3u,
                                                 int* __restrict__ bsum) {
  int c = blockIdx.x, g = blockIdx.y;
  const unsigned short* deg = deg3u + (size_t)g * NN;
  int base = c * SCHUNK;
  int s = 0;
  for (int i = threadIdx.x; i < SCHUNK; i += 256) {
    int idx = base + i;
    s += (idx < NN) ? (int)deg[idx] : 0;
  }
#pragma unroll
  for (int o = 32; o; o >>= 1) s += __shfl_down(s, o, 64);
  __shared__ int ws[4];
  if ((threadIdx.x & 63) == 0) ws[threadIdx.x >> 6] = s;
  __syncthreads();
  if (threadIdx.x == 0) bsum[g * NCHUNK + c] = ws[0] + ws[1] + ws[2] + ws[3];
}

// grid (3), block 128: exclusive scan of the NCHUNK chunk sums (in place)
__global__ __launch_bounds__(128) void scan_mid(int* __restrict__ bsum) {
  int g = blockIdx.x;
  int t = threadIdx.x;
  int v = (t < NCHUNK) ? bsum[g * NCHUNK + t] : 0;
  int lane = t & 63, wv = t >> 6;
  int x = v;
#pragma unroll
  for (int o = 1; o < 64; o <<= 1) {
    int tt = __shfl_up(x, o, 64);
    if (lane >= o) x += tt;
  }
  __shared__ int w0sum;
  if (wv == 0 && lane == 63) w0sum = x;
  __syncthreads();
  int excl = x - v + (wv ? w0sum : 0);
  if (t < NCHUNK) bsum[g * NCHUNK + t] = excl;
}

// grid (NCHUNK, 3), block 1024: per-chunk scan + chunk base -> offs
__global__ __launch_bounds__(1024) void scan_final(const unsigned short* __restrict__ deg3u,
    const int* __restrict__ bsum, int* __restrict__ offs3) {
  int c = blockIdx.x, g = blockIdx.y;
  const unsigned short* deg = deg3u + (size_t)g * NN;
  int* offs = offs3 + (size_t)g * (NN + 1);
  int t = threadIdx.x;
  int idx = c * SCHUNK + t;
  int v = (idx < NN) ? (int)deg[idx] : 0;
  int lane = t & 63, wv = t >> 6;
  int x = v;
#pragma unroll
  for (int o = 1; o < 64; o <<= 1) {
    int tt = __shfl_up(x, o, 64);
    if (lane >= o) x += tt;
  }
  __shared__ int ws[16];
  if (lane == 63) ws[wv] = x;
  __syncthreads();
  int woff = 0;
  for (int j = 0; j < wv; ++j) woff += ws[j];
  if (idx < NN) offs[idx] = bsum[g * NCHUNK + c] + woff + x - v;
  if (idx == NN - 1) offs[NN] = EE;
}

__global__ void fill_csr(const int* __restrict__ src, const int* __restrict__ dst,
                         const float* __restrict__ dinv, const int* __restrict__ offs,
                         int* __restrict__ fillc, unsigned long long* __restrict__ ent,
                         int e) {
  int i = blockIdx.x * 256 + threadIdx.x;
  if (i >= e) return;
  int d = dst[i], s = src[i];
  int pos = offs[d] + atomicAdd(&fillc[d], 1);
  unsigned long long w = (unsigned long long)(unsigned)__float_as_int(dinv[s]);
  ent[pos] = (w << 32) | (unsigned)s;
}

// ---------------------------------------------------------------------------
// dtype converters
// ---------------------------------------------------------------------------
__global__ void conv_bf(const float* __restrict__ in, unsigned* __restrict__ out, int n4) {
  int i = blockIdx.x * 256 + threadIdx.x;
  if (i >= n4) return;
  float4 v = ((const float4*)in)[i];
  ((uint2*)out)[i] = make_uint2(pack2(v.x, v.y), pack2(v.z, v.w));
}

// W[K][256] fp32 -> Wt[256][K] bf16 (transposed for gemm B^T operand)
__global__ void conv_wt(const float* __restrict__ W, unsigned short* __restrict__ Wt, int K) {
  int i = blockIdx.x * 256 + threadIdx.x;
  if (i >= 256 * K) return;
  int nn = i / K, kk = i - nn * K;
  Wt[i] = f2b(W[(size_t)kk * 256 + nn]);
}

// ---------------------------------------------------------------------------
// Aggregation (bf16 rows, fp32 accumulate, bf16 out):
// y[v] = dinv[v] * ( sum_e dinv[src]*x[src] + dinv[v]*x[v] )
// Wave-per-node, v wave-uniform via readfirstlane -> scalar CSR walk.
// ---------------------------------------------------------------------------
__global__ __launch_bounds__(256) void agg256_bf(const unsigned short* __restrict__ x,
    const unsigned long long* __restrict__ ent, const int* __restrict__ offs,
    const float* __restrict__ dinv, unsigned short* __restrict__ y, int n) {
  int v = (blockIdx.x * 256 + threadIdx.x) >> 6;
  v = __builtin_amdgcn_readfirstlane(v);
  int lane = threadIdx.x & 63;
  if (v >= n) return;
  float dv = dinv[v];
  const uint2* selfp = (const uint2*)(x + ((size_t)(unsigned)v << 8)) + lane;
  uint2 self = *selfp;
  float a0 = dv * blo(self.x), a1 = dv * bhi(self.x);
  float a2 = dv * blo(self.y), a3 = dv * bhi(self.y);
  int s = offs[v], e = offs[v + 1];
  int i = s;
  for (; i + 3 < e; i += 4) {
    unsigned long long p0 = ent[i], p1 = ent[i + 1], p2 = ent[i + 2], p3 = ent[i + 3];
    unsigned s0 = (unsigned)p0, s1 = (unsigned)p1, s2 = (unsigned)p2, s3 = (unsigned)p3;
    float w0 = __uint_as_float((unsigned)(p0 >> 32));
    float w1 = __uint_as_float((unsigned)(p1 >> 32));
    float w2 = __uint_as_float((unsigned)(p2 >> 32));
    float w3 = __uint_as_float((unsigned)(p3 >> 32));
    uint2 r0 = *((const uint2*)(x + ((size_t)s0 << 8)) + lane);
    uint2 r1 = *((const uint2*)(x + ((size_t)s1 << 8)) + lane);
    uint2 r2 = *((const uint2*)(x + ((size_t)s2 << 8)) + lane);
    uint2 r3 = *((const uint2*)(x + ((size_t)s3 << 8)) + lane);
    a0 += w0 * blo(r0.x); a1 += w0 * bhi(r0.x); a2 += w0 * blo(r0.y); a3 += w0 * bhi(r0.y);
    a0 += w1 * blo(r1.x); a1 += w1 * bhi(r1.x); a2 += w1 * blo(r1.y); a3 += w1 * bhi(r1.y);
    a0 += w2 * blo(r2.x); a1 += w2 * bhi(r2.x); a2 += w2 * blo(r2.y); a3 += w2 * bhi(r2.y);
    a0 += w3 * blo(r3.x); a1 += w3 * bhi(r3.x); a2 += w3 * blo(r3.y); a3 += w3 * bhi(r3.y);
  }
  for (; i < e; ++i) {
    unsigned long long p0 = ent[i];
    unsigned s0 = (unsigned)p0;
    float w0 = __uint_as_float((unsigned)(p0 >> 32));
    uint2 r0 = *((const uint2*)(x + ((size_t)s0 << 8)) + lane);
    a0 += w0 * blo(r0.x); a1 += w0 * bhi(r0.x); a2 += w0 * blo(r0.y); a3 += w0 * bhi(r0.y);
  }
  uint2* yp = (uint2*)(y + ((size_t)(unsigned)v << 8)) + lane;
  *yp = make_uint2(pack2(dv * a0, dv * a1), pack2(dv * a2, dv * a3));
}

__global__ __launch_bounds__(256) void agg128_bf(const unsigned short* __restrict__ x,
    const unsigned long long* __restrict__ ent, const int* __restrict__ offs,
    const float* __restrict__ dinv, unsigned short* __restrict__ y, int n) {
  int v = (blockIdx.x * 256 + threadIdx.x) >> 6;
  v = __builtin_amdgcn_readfirstlane(v);
  int lane = threadIdx.x & 63;
  if (v >= n) return;
  float dv = dinv[v];
  const unsigned* selfp = (const unsigned*)(x + ((size_t)(unsigned)v << 7)) + lane;
  unsigned self = *selfp;
  float a0 = dv * blo(self), a1 = dv * bhi(self);
  int s = offs[v], e = offs[v + 1];
  int i = s;
  for (; i + 3 < e; i += 4) {
    unsigned long long p0 = ent[i], p1 = ent[i + 1], p2 = ent[i + 2], p3 = ent[i + 3];
    unsigned s0 = (unsigned)p0, s1 = (unsigned)p1, s2 = (unsigned)p2, s3 = (unsigned)p3;
    float w0 = __uint_as_float((unsigned)(p0 >> 32));
    float w1 = __uint_as_float((unsigned)(p1 >> 32));
    float w2 = __uint_as_float((unsigned)(p2 >> 32));
    float w3 = __uint_as_float((unsigned)(p3 >> 32));
    unsigned r0 = *((const unsigned*)(x + ((size_t)s0 << 7)) + lane);
    unsigned r1 = *((const unsigned*)(x + ((size_t)s1 << 7)) + lane);
    unsigned r2 = *((const unsigned*)(x + ((size_t)s2 << 7)) + lane);
    unsigned r3 = *((const unsigned*)(x + ((size_t)s3 << 7)) + lane);
    a0 += w0 * blo(r0); a1 += w0 * bhi(r0);
    a0 += w1 * blo(r1); a1 += w1 * bhi(r1);
    a0 += w2 * blo(r2); a1 += w2 * bhi(r2);
    a0 += w3 * blo(r3); a1 += w3 * bhi(r3);
  }
  for (; i < e; ++i) {
    unsigned long long p0 = ent[i];
    unsigned s0 = (unsigned)p0;
    float w0 = __uint_as_float((unsigned)(p0 >> 32));
    unsigned r0 = *((const unsigned*)(x + ((size_t)s0 << 7)) + lane);
    a0 += w0 * blo(r0); a1 += w0 * bhi(r0);
  }
  unsigned* yp = (unsigned*)(y + ((size_t)(unsigned)v << 7)) + lane;
  *yp = pack2(dv * a0, dv * a1);
}

// ---------------------------------------------------------------------------
// MFMA bf16 GEMM: C[M,256] = A[M,K]bf16 @ Wt[256,K]bf16^T + bias, opt ReLU,
// C stored bf16. 128x128 tile, BK=32, 256 thr = 4 waves (2x2), each wave
// 64x64 = 4x4 grid of 16x16x32 mfma. C/D layout: col=lane&15, row=quad*4+reg.
// ---------------------------------------------------------------------------
#define LDA 40  // 32 + 8 bf16 pad -> 80B row stride, keeps 16B align
__global__ __launch_bounds__(256) void gemm_mfma(
    const unsigned short* __restrict__ A, const unsigned short* __restrict__ Bt,
    const float* __restrict__ bias, unsigned short* __restrict__ C,
    int M, int K, int do_relu) {
  __shared__ unsigned short As[128 * LDA];
  __shared__ unsigned short Bs[128 * LDA];
  int tid = threadIdx.x;
  int row0 = blockIdx.x * 128;
  int col0 = blockIdx.y * 128;
  int wave = tid >> 6, lane = tid & 63;
  int wm = wave >> 1, wn = wave & 1;
  int lr = lane & 15, quad = lane >> 4;

  f32x4 acc[4][4];
#pragma unroll
  for (int i = 0; i < 4; ++i)
#pragma unroll
    for (int j = 0; j < 4; ++j) acc[i][j] = (f32x4){0.f, 0.f, 0.f, 0.f};

  for (int k0 = 0; k0 < K; k0 += 32) {
#pragma unroll
    for (int p = 0; p < 2; ++p) {
      int i = tid + p * 256;          // 0..511
      int r = i >> 2, q = i & 3;      // 128 rows x 4 16B-quads
      int row = row0 + r; if (row >= M) row = M - 1;
      uint4 va = *(const uint4*)(A + (size_t)row * K + k0 + q * 8);
      *(uint4*)&As[r * LDA + q * 8] = va;
      uint4 vb = *(const uint4*)(Bt + (size_t)(col0 + r) * K + k0 + q * 8);
      *(uint4*)&Bs[r * LDA + q * 8] = vb;
    }
    __syncthreads();
    bf16x8 af[4], bf[4];
#pragma unroll
    for (int mi = 0; mi < 4; ++mi)
      af[mi] = *(const bf16x8*)&As[(wm * 64 + mi * 16 + lr) * LDA + quad * 8];
#pragma unroll
    for (int ni = 0; ni < 4; ++ni)
      bf[ni] = *(const bf16x8*)&Bs[(wn * 64 + ni * 16 + lr) * LDA + quad * 8];
#pragma unroll
    for (int mi = 0; mi < 4; ++mi)
#pragma unroll
      for (int ni = 0; ni < 4; ++ni)
        acc[mi][ni] = __builtin_amdgcn_mfma_f32_16x16x32_bf16(af[mi], bf[ni], acc[mi][ni], 0, 0, 0);
    __syncthreads();
  }

  // epilogue: bias + optional relu, store bf16
  float bv[4];
#pragma unroll
  for (int ni = 0; ni < 4; ++ni) bv[ni] = bias[col0 + wn * 64 + ni * 16 + lr];
#pragma unroll
  for (int mi = 0; mi < 4; ++mi) {
#pragma unroll
    for (int r = 0; r < 4; ++r) {
      int grow = row0 + wm * 64 + mi * 16 + quad * 4 + r;
      if (grow < M) {
#pragma unroll
        for (int ni = 0; ni < 4; ++ni) {
          float v = acc[mi][ni][r] + bv[ni];
          if (do_relu) v = fmaxf(v, 0.f);
          C[(size_t)grow * 256 + col0 + wn * 64 + ni * 16 + lr] = f2b(v);
        }
      }
    }
  }
}

// ---------------------------------------------------------------------------
// Pooling: batch is sorted; per-block run-length accumulate then atomicAdd.
// Counting fused (thread f==0 adds run length once per run).
// ---------------------------------------------------------------------------
__global__ __launch_bounds__(256) void pool_sum_bf(const unsigned short* __restrict__ h,
    const int* __restrict__ batch, float* __restrict__ sums,
    float* __restrict__ cnts, int n) {
  int f = threadIdx.x;           // 0..255 feature
  int v0 = blockIdx.x * 128;
  if (v0 >= n) return;
  int vend = min(v0 + 128, n);
  int cur = batch[v0];
  float acc = 0.f;
  int cnt = 0;
  for (int v = v0; v < vend; ++v) {
    int b = batch[v];
    if (b != cur) {
      atomicAdd(&sums[cur * 256 + f], acc);
      if (f == 0) atomicAdd(&cnts[cur], (float)cnt);
      acc = 0.f; cnt = 0; cur = b;
    }
    acc += b2f(h[(size_t)v * 256 + f]);
    cnt++;
  }
  atomicAdd(&sums[cur * 256 + f], acc);
  if (f == 0) atomicAdd(&cnts[cur], (float)cnt);
}

// z[g,f] = (sums[g,:]/max(cnt,1)) @ lin0_W[:,f] + lin0_b[f]   (64 blocks x 128 thr)
__global__ __launch_bounds__(128) void pool_lin(const float* __restrict__ sums,
    const float* __restrict__ cnts, const float* __restrict__ W128,
    const float* __restrict__ b128, float* __restrict__ z) {
  int g = blockIdx.x, f = threadIdx.x;
  float inv = 1.0f / fmaxf(cnts[g], 1.0f);
  float acc = 0.f;
  for (int k = 0; k < 256; ++k)
    acc += (sums[g * 256 + k] * inv) * W128[k * 128 + f];
  z[g * 128 + f] = acc + b128[f];
}

// ---------------------------------------------------------------------------
// Final triplet outputs. out layout: z0[8192] z1[8192] z2[8192] correct[1]
// score_p[64] score_n[64] correct_score[1]
// ---------------------------------------------------------------------------
__global__ __launch_bounds__(64) void final_triplet(const float* __restrict__ z,
    const float* __restrict__ lin_W, const float* __restrict__ lin_b,
    float* __restrict__ out) {
  int g = threadIdx.x;  // 0..63, one wave
  const float* z0 = z;
  const float* z1 = z + 8192;
  const float* z2 = z + 16384;
  float dp = 0.f, dn = 0.f;
  float y1 = lin_b[0], y2 = lin_b[0];
  for (int f = 0; f < 128; ++f) {
    float a = z0[g * 128 + f], b = z1[g * 128 + f], c = z2[g * 128 + f];
    float d1 = a - b + 1e-6f, d2 = a - c + 1e-6f;
    dp += d1 * d1; dn += d2 * d2;
    float w0 = lin_W[f], w1 = lin_W[128 + f];
    y1 += a * w0 + b * w1;
    y2 += a * w0 + c * w1;
  }
  dp = sqrtf(dp); dn = sqrtf(dn);
  float sp = 1.f / (1.f + expf(-y1));
  float sn = 1.f / (1.f + expf(-y2));
  out[24577 + g] = sp;
  out[24641 + g] = sn;
  unsigned long long m1 = __ballot(dn - dp > 0.f);
  unsigned long long m2 = __ballot(sp - sn > 0.f);
  if (g == 0) {
    out[24576] = (float)__popcll(m1);
    out[24705] = (float)__popcll(m2);
  }
}

// ---------------------------------------------------------------------------
extern "C" void kernel_launch(void* const* d_in, const int* in_sizes, int n_in,
                              void* d_out, int out_size, void* d_ws, size_t ws_size,
                              hipStream_t stream) {
  const float* xin[3]  = {(const float*)d_in[0], (const float*)d_in[1], (const float*)d_in[2]};
  const int* ei[3]     = {(const int*)d_in[3], (const int*)d_in[4], (const int*)d_in[5]};
  const int* batch[3]  = {(const int*)d_in[6], (const int*)d_in[7], (const int*)d_in[8]};
  const float* W0 = (const float*)d_in[9],  *b0 = (const float*)d_in[10];
  const float* W1 = (const float*)d_in[11], *b1 = (const float*)d_in[12];
  const float* W2 = (const float*)d_in[13], *b2 = (const float*)d_in[14];
  const float* lin0W = (const float*)d_in[15], *lin0b = (const float*)d_in[16];
  const float* linW  = (const float*)d_in[17], *linb  = (const float*)d_in[18];
  float* out = (float*)d_out;

  // workspace carve (16B-aligned by construction)
  unsigned short* ybf = (unsigned short*)d_ws;        // N*256 bf16 = 51.2 MB
  unsigned short* hbf = ybf + (size_t)NN * 256;       // N*256 bf16 = 51.2 MB
  unsigned short* xbf = hbf + (size_t)NN * 256;       // N*128 bf16 = 25.6 MB
  unsigned long long* ent = (unsigned long long*)(xbf + (size_t)NN * 128);  // E*8B
  unsigned short* Wt0 = (unsigned short*)(ent + EE);  // 256*128
  unsigned short* Wt1 = Wt0 + 256 * 128;              // 256*256
  unsigned short* Wt2 = Wt1 + 256 * 256;              // 256*256
  // zeroed region: fillc3, sums3, cnts3 (contiguous)
  int* fillc3 = (int*)(Wt2 + 256 * 256);              // 3N ints
  float* sums3 = (float*)(fillc3 + 3 * NN);           // 3*64*256 floats
  float* cnts3 = sums3 + 3 * 64 * 256;                // 3*64 floats
  int zero_elems = 3 * NN + 3 * 64 * 256 + 3 * 64;
  float* dinv3 = cnts3 + 3 * 64;                      // 3N floats
  int* offs3 = (int*)(dinv3 + 3 * NN);                // 3*(N+1) ints
  unsigned* deg3w = (unsigned*)(offs3 + 3 * (NN + 1)); // 3*(N/2) packed ushort words
  int* bsum = (int*)(deg3w + 3 * (NN / 2));           // 3*NCHUNK ints
  unsigned* partials = (unsigned*)(bsum + 3 * NCHUNK); // 3*NPASS*HB*WPB = 11 MB
  const unsigned short* deg3u = (const unsigned short*)deg3w;

  const int EB = (EE + 255) / 256;
  dim3 ggrid((NN + 127) / 128, 2);

  // weight conversion (once per launch)
  conv_wt<<<(256 * 128 + 255) / 256, 256, 0, stream>>>(W0, Wt0, 128);
  conv_wt<<<(256 * 256 + 255) / 256, 256, 0, stream>>>(W1, Wt1, 256);
  conv_wt<<<(256 * 256 + 255) / 256, 256, 0, stream>>>(W2, Wt2, 256);

  // batched CSR prep for all 3 graphs: LDS histogram + hierarchical scan
  zero_int<<<(zero_elems + 255) / 256, 256, 0, stream>>>(fillc3, zero_elems);
  hist_part<<<dim3(HB, NPASS, 3), 256, 0, stream>>>(ei[0] + EE, ei[1] + EE, ei[2] + EE, partials);
  hist_reduce<<<dim3(WPB / 256, NPASS, 3), 256, 0, stream>>>(partials, deg3w);
  calc_dinv3<<<(3 * NN + 255) / 256, 256, 0, stream>>>(deg3u, dinv3, 3 * NN);
  scan_part<<<dim3(NCHUNK, 3), 256, 0, stream>>>(deg3u, bsum);
  scan_mid<<<3, 128, 0, stream>>>(bsum);
  scan_final<<<dim3(NCHUNK, 3), 1024, 0, stream>>>(deg3u, bsum, offs3);

  for (int g = 0; g < 3; ++g) {
    const int* src = ei[g];
    const int* dst = ei[g] + EE;
    const float* dinv = dinv3 + (size_t)g * NN;
    const int* offs = offs3 + (size_t)g * (NN + 1);

    fill_csr<<<EB, 256, 0, stream>>>(src, dst, dinv, offs, fillc3 + (size_t)g * NN, ent, EE);

    // convert input features to bf16
    conv_bf<<<(NN * 128 / 4 + 255) / 256, 256, 0, stream>>>(xin[g], (unsigned*)xbf, NN * 128 / 4);

    // layer 0: aggregate (F=128) then MFMA GEMM K=128 -> h (ReLU)
    agg128_bf<<<(NN + 3) / 4, 256, 0, stream>>>(xbf, ent, offs, dinv, ybf, NN);
    gemm_mfma<<<ggrid, 256, 0, stream>>>(ybf, Wt0, b0, hbf, NN, 128, 1);
    // layer 1
    agg256_bf<<<(NN + 3) / 4, 256, 0, stream>>>(hbf, ent, offs, dinv, ybf, NN);
    gemm_mfma<<<ggrid, 256, 0, stream>>>(ybf, Wt1, b1, hbf, NN, 256, 1);
    // layer 2 (no relu)
    agg256_bf<<<(NN + 3) / 4, 256, 0, stream>>>(hbf, ent, offs, dinv, ybf, NN);
    gemm_mfma<<<ggrid, 256, 0, stream>>>(ybf, Wt2, b2, hbf, NN, 256, 0);

    // pool (+fused count) + lin0 -> z_g written directly into d_out
    pool_sum_bf<<<(NN + 127) / 128, 256, 0, stream>>>(hbf, batch[g],
        sums3 + (size_t)g * 64 * 256, cnts3 + (size_t)g * 64, NN);
    pool_lin<<<64, 128, 0, stream>>>(sums3 + (size_t)g * 64 * 256, cnts3 + (size_t)g * 64,
        lin0W, lin0b, out + g * 8192);
  }

  final_triplet<<<1, 64, 0, stream>>>(out, linW, linb, out);
}